// Round 12
// baseline (2705.511 us; speedup 1.0000x reference)
//
#include <hip/hip_runtime.h>

// DGCNN inference, MI355X gfx950. B=8, N=4096, K=20. fp32 in/out.
// knn: MFMA distance GEMM, XCD-pinned batches, full j-scan. Selection via
// PER-LANE PRIVATE LDS STASH: append = predicated store + bump (zero
// ballots); one ballot/jt drain check; drain = proven 128-wide bitonic over
// the row's fixed 116 slots (top20[20] + stash[6][16], INFK-padded
// invariant), tau tightened monotonically from sorted 20th element.
// EdgeConv factored (featg + gather-max). conv5: fp16 hi/lo split MFMA.

constexpr int NB  = 8;
constexpr int NPT = 4096;
constexpr int KNB = 20;
constexpr int ROWU = 116;  // u64 per row: top20[20] + stash[6][16]

typedef _Float16 half8 __attribute__((ext_vector_type(8)));
typedef float f32x4 __attribute__((ext_vector_type(4)));

// monotone float->uint map (order-preserving, handles negatives)
__device__ __forceinline__ unsigned int fmono(float f) {
  unsigned int u = __float_as_uint(f);
  return u ^ ((unsigned int)(((int)u) >> 31) | 0x80000000u);
}

// ---- drain: sort row's 116 slots (INFK-padded), keep top-20, reset stash --
// Proven 128-wide bitonic (asc A + desc C -> min -> merge). Returns each
// lane's sorted element (top-20 in lanes 0..19). Writes new top20 back and
// resets stash slots [20,116) to INFK (preserves the valid-or-INFK invariant).
__device__ __attribute__((noinline)) unsigned long long drain_row(int row,
                                                                  int lane) {
  extern __shared__ char smem[];
  unsigned long long* rb = (unsigned long long*)smem + (size_t)row * ROWU;
  unsigned long long a = rb[lane];
  unsigned long long c = (lane + 64 < ROWU) ? rb[lane + 64] : ~0ull;
#pragma unroll
  for (int k = 2; k <= 64; k <<= 1) {
#pragma unroll
    for (int j = k >> 1; j > 0; j >>= 1) {
      const bool tm = (((lane & k) == 0) == ((lane & j) == 0));
      const unsigned long long oa = __shfl_xor(a, j, 64);
      a = ((a < oa) == tm) ? a : oa;  // ascending network
      const unsigned long long oc = __shfl_xor(c, j, 64);
      c = ((c < oc) == tm) ? oc : c;  // inverted -> descending
    }
  }
  unsigned long long m = a < c ? a : c;  // 64 smallest (bitonic)
#pragma unroll
  for (int j = 32; j > 0; j >>= 1) {  // merge to ascending
    const unsigned long long o = __shfl_xor(m, j, 64);
    const bool low = (lane & j) == 0;
    m = ((m < o) == low) ? m : o;
  }
  if (lane < 20) rb[lane] = m;  // new top20
#pragma unroll
  for (int idx = 20 + lane; idx < ROWU; idx += 64) rb[idx] = ~0ull;
  return m;
}

// ---- convert xyz fp32 [B][N][3] -> fp32 [B][N][4] (pad 0) ----
__global__ __launch_bounds__(256) void cvt_xyz(const float* __restrict__ xyz,
                                               float* __restrict__ x0) {
  const int t = blockIdx.x * 256 + threadIdx.x;  // < B*N
  float4 v;
  v.x = xyz[t * 3 + 0];
  v.y = xyz[t * 3 + 1];
  v.z = xyz[t * 3 + 2];
  v.w = 0.0f;
  *(float4*)(x0 + (size_t)t * 4) = v;
}

// ---- sq norms + fp16 hi/lo split of a [B*N][64] fp32 feature map ----
__global__ __launch_bounds__(256) void sqsplit(const float* __restrict__ x,
                                               float* __restrict__ sqo,
                                               unsigned short* __restrict__ xhi,
                                               unsigned short* __restrict__ xlo) {
  const int t = blockIdx.x * 256 + threadIdx.x;  // < B*N*4
  const int p = t >> 2, c = t & 3;
  const float* src = x + (size_t)p * 64 + c * 16;
  float s = 0.0f;
  unsigned short hb[16], lb[16];
#pragma unroll
  for (int e = 0; e < 16; e += 4) {
    const float4 v = *(const float4*)(src + e);
    const float vv[4] = {v.x, v.y, v.z, v.w};
#pragma unroll
    for (int u = 0; u < 4; ++u) {
      const float f = vv[u];
      s = fmaf(f, f, s);
      const _Float16 h = (_Float16)f;
      const _Float16 l = (_Float16)(f - (float)h);
      hb[e + u] = __builtin_bit_cast(unsigned short, h);
      lb[e + u] = __builtin_bit_cast(unsigned short, l);
    }
  }
  unsigned short* dh = xhi + (size_t)p * 64 + c * 16;
  unsigned short* dl = xlo + (size_t)p * 64 + c * 16;
  *(uint4*)dh = *(uint4*)hb;
  *(uint4*)(dh + 8) = *(uint4*)(hb + 8);
  *(uint4*)dl = *(uint4*)lb;
  *(uint4*)(dl + 8) = *(uint4*)(lb + 8);
  s += __shfl_xor(s, 1, 64);
  s += __shfl_xor(s, 2, 64);
  if (c == 0) sqo[p] = s;
}

// ---- knn layer 1 (D=3): direct distances, per-lane stash selection ----
// Grid 512: b = bid&7 (XCD pin), i0 = (bid>>3)*64. dyn LDS 59392 B.
__global__ __launch_bounds__(256, 2) void knn3(const float* __restrict__ x0,
                                               int* __restrict__ idxout) {
  const int bid = blockIdx.x;
  const int b = bid & 7;
  const int i0 = (bid >> 3) * 64;
  const int tid = threadIdx.x, w = tid >> 6, lane = tid & 63;
  const int l15 = lane & 15, quad = lane >> 4;
  extern __shared__ char smem[];
  unsigned long long* S = (unsigned long long*)smem;
  const float* xb = x0 + (size_t)b * (NPT * 4);

  {  // init wave-private rows to INFK (no barrier needed)
    unsigned long long* wb = S + (size_t)(w * 16) * ROWU;
    for (int idx = lane; idx < 16 * ROWU; idx += 64) wb[idx] = ~0ull;
  }

  float xix[4], xiy[4], xiz[4];
#pragma unroll
  for (int r = 0; r < 4; ++r) {
    const float4 v =
        *(const float4*)(xb + (size_t)(i0 + w * 16 + quad * 4 + r) * 4);
    xix[r] = v.x;
    xiy[r] = v.y;
    xiz[r] = v.z;
  }

  int soff[4];
#pragma unroll
  for (int r = 0; r < 4; ++r)
    soff[r] = (w * 16 + quad * 4 + r) * ROWU + 20 + l15;

  unsigned long long tau[4] = {~0ull, ~0ull, ~0ull, ~0ull};
  int c[4] = {0, 0, 0, 0};

  for (int jt = 0; jt < NPT / 64; ++jt) {
    const int j0 = jt * 64;
    float4 xj[4];
#pragma unroll
    for (int nj = 0; nj < 4; ++nj)
      xj[nj] = *(const float4*)(xb + (size_t)(j0 + nj * 16 + l15) * 4);
#pragma unroll
    for (int r = 0; r < 4; ++r) {
#pragma unroll
      for (int nj = 0; nj < 4; ++nj) {
        const float dx = xj[nj].x - xix[r];
        const float dy = xj[nj].y - xiy[r];
        const float dz = xj[nj].z - xiz[r];
        const float dd = fmaf(dx, dx, fmaf(dy, dy, dz * dz));
        const unsigned long long key =
            ((unsigned long long)fmono(dd) << 32) |
            (unsigned int)(j0 + nj * 16 + l15);
        if (key < tau[r]) {
          S[soff[r] + c[r] * 16] = key;
          ++c[r];
        }
      }
    }
    const int cm = max(max(c[0], c[1]), max(c[2], c[3]));
    if (__ballot(cm > 2) != 0ull) {  // rare: drain rows nearing capacity
#pragma unroll 1
      for (int r = 0; r < 4; ++r) {
        const unsigned long long mr = __ballot(c[r] > 2);
        if (mr == 0ull) continue;
#pragma unroll 1
        for (int q = 0; q < 4; ++q) {
          if ((mr >> (q * 16)) & 0xFFFFull) {
            const unsigned long long m = drain_row(w * 16 + q * 4 + r, lane);
            const unsigned long long t19 = __shfl(m, 19, 64);
            if (quad == q) {
              tau[r] = tau[r] < t19 ? tau[r] : t19;
              c[r] = 0;
            }
          }
        }
      }
    }
  }
#pragma unroll 1
  for (int rw = 0; rw < 16; ++rw) {
    const unsigned long long m = drain_row(w * 16 + rw, lane);
    const int i = i0 + w * 16 + rw;
    if (lane < 20)
      idxout[((size_t)(b * NPT + i)) * KNB + lane] = (int)(unsigned int)m;
  }
}

// ---- knn layers 2-4 (D=64): fp16x2-split MFMA, per-lane stash selection --
// Grid 512: b = bid&7 (XCD pin -> 2MB/batch L2-resident). dyn LDS 59392 B.
__global__ __launch_bounds__(256, 2) void knn_mfma(
    const unsigned short* __restrict__ xhi16,
    const unsigned short* __restrict__ xlo16,
    const float* __restrict__ sqn, int* __restrict__ idxout) {
  const int bid = blockIdx.x;
  const int b = bid & 7;
  const int i0 = (bid >> 3) * 64;
  const int tid = threadIdx.x, w = tid >> 6, lane = tid & 63;
  const int l15 = lane & 15, quad = lane >> 4;
  extern __shared__ char smem[];
  unsigned long long* S = (unsigned long long*)smem;

  {  // init wave-private rows to INFK (no barrier needed)
    unsigned long long* wb = S + (size_t)(w * 16) * ROWU;
    for (int idx = lane; idx < 16 * ROWU; idx += 64) wb[idx] = ~0ull;
  }

  const half8* Hb = (const half8*)(xhi16 + (size_t)b * NPT * 64);
  const half8* Lb = (const half8*)(xlo16 + (size_t)b * NPT * 64);
  const float* sqb = sqn + b * NPT;

  const int ia = i0 + w * 16 + l15;
  const half8 ah0 = Hb[(size_t)ia * 8 + quad];
  const half8 ah1 = Hb[(size_t)ia * 8 + 4 + quad];
  const half8 al0 = Lb[(size_t)ia * 8 + quad];
  const half8 al1 = Lb[(size_t)ia * 8 + 4 + quad];

  int soff[4];
#pragma unroll
  for (int r = 0; r < 4; ++r)
    soff[r] = (w * 16 + quad * 4 + r) * ROWU + 20 + l15;

  unsigned long long tau[4] = {~0ull, ~0ull, ~0ull, ~0ull};
  int c[4] = {0, 0, 0, 0};

  for (int jt = 0; jt < NPT / 64; ++jt) {
    const int j0 = jt * 64;
    float sq4[4];
#pragma unroll
    for (int nj = 0; nj < 4; ++nj) sq4[nj] = sqb[j0 + nj * 16 + l15];
    f32x4 acc[4];
#pragma unroll
    for (int nj = 0; nj < 4; ++nj) {
      const int jb = j0 + nj * 16 + l15;
      const half8 bh0 = Hb[(size_t)jb * 8 + quad];
      const half8 bh1 = Hb[(size_t)jb * 8 + 4 + quad];
      const half8 bl0 = Lb[(size_t)jb * 8 + quad];
      const half8 bl1 = Lb[(size_t)jb * 8 + 4 + quad];
      f32x4 a = {0.0f, 0.0f, 0.0f, 0.0f};
      a = __builtin_amdgcn_mfma_f32_16x16x32_f16(al0, bh0, a, 0, 0, 0);
      a = __builtin_amdgcn_mfma_f32_16x16x32_f16(al1, bh1, a, 0, 0, 0);
      a = __builtin_amdgcn_mfma_f32_16x16x32_f16(ah0, bl0, a, 0, 0, 0);
      a = __builtin_amdgcn_mfma_f32_16x16x32_f16(ah1, bl1, a, 0, 0, 0);
      a = __builtin_amdgcn_mfma_f32_16x16x32_f16(ah0, bh0, a, 0, 0, 0);
      a = __builtin_amdgcn_mfma_f32_16x16x32_f16(ah1, bh1, a, 0, 0, 0);
      acc[nj] = a;
    }
    // C layout: row = quad*4+r, col = nj*16+l15
#pragma unroll
    for (int r = 0; r < 4; ++r) {
#pragma unroll
      for (int nj = 0; nj < 4; ++nj) {
        const float dd = fmaf(-2.0f, acc[nj][r], sq4[nj]);
        const unsigned long long key =
            ((unsigned long long)fmono(dd) << 32) |
            (unsigned int)(j0 + nj * 16 + l15);
        if (key < tau[r]) {
          S[soff[r] + c[r] * 16] = key;
          ++c[r];
        }
      }
    }
    const int cm = max(max(c[0], c[1]), max(c[2], c[3]));
    if (__ballot(cm > 2) != 0ull) {  // rare: drain rows nearing capacity
#pragma unroll 1
      for (int r = 0; r < 4; ++r) {
        const unsigned long long mr = __ballot(c[r] > 2);
        if (mr == 0ull) continue;
#pragma unroll 1
        for (int q = 0; q < 4; ++q) {
          if ((mr >> (q * 16)) & 0xFFFFull) {
            const unsigned long long m = drain_row(w * 16 + q * 4 + r, lane);
            const unsigned long long t19 = __shfl(m, 19, 64);
            if (quad == q) {
              tau[r] = tau[r] < t19 ? tau[r] : t19;
              c[r] = 0;
            }
          }
        }
      }
    }
  }
#pragma unroll 1
  for (int rw = 0; rw < 16; ++rw) {
    const unsigned long long m = drain_row(w * 16 + rw, lane);
    const int i = i0 + w * 16 + rw;
    if (lane < 20)
      idxout[((size_t)(b * NPT + i)) * KNB + lane] = (int)(unsigned int)m;
  }
}

// ---- featg3: Y[p, c] = wa_c . x0[p]  (DIN=3), XCD-pinned ----
__global__ __launch_bounds__(256) void featg3(const float* __restrict__ x0,
                                              const float* __restrict__ W,
                                              float* __restrict__ Y) {
  const int lane = threadIdx.x & 63;
  const int bid = blockIdx.x;  // 2048 = 8 x 256
  const int p0 =
      ((bid & 7) << 12) + ((bid >> 3) * 4 + (threadIdx.x >> 6)) * 4;
  const float* wr = W + lane * 6;
  const float w0 = wr[0], w1 = wr[1], w2 = wr[2];
#pragma unroll
  for (int r = 0; r < 4; ++r) {
    const float4 v = *(const float4*)(x0 + (size_t)(p0 + r) * 4);
    Y[(size_t)(p0 + r) * 64 + lane] = w0 * v.x + w1 * v.y + w2 * v.z;
  }
}

// ---- featg64: Y[p, c'] = sum_d X[p][d] * W[(co+c')][d], XCD-pinned ----
__global__ __launch_bounds__(256) void featg64(const float* __restrict__ X,
                                               const float* __restrict__ W,
                                               int co, float* __restrict__ Y) {
  __shared__ float Xt[64][68];  // [d][p]
  __shared__ float Wt[64][68];  // [d][c]
  const int tid = threadIdx.x;
  const int bid = blockIdx.x;  // 512 = 8 x 64
  const int n0 = ((bid & 7) << 12) + (bid >> 3) * 64;
  const int pc = tid & 63, dg = tid >> 6;  // dg 0..3
#pragma unroll
  for (int rep = 0; rep < 4; ++rep) {
    const int d0 = dg * 16 + rep * 4;
    const float4 xv = *(const float4*)(X + (size_t)(n0 + pc) * 64 + d0);
    Xt[d0 + 0][pc] = xv.x; Xt[d0 + 1][pc] = xv.y;
    Xt[d0 + 2][pc] = xv.z; Xt[d0 + 3][pc] = xv.w;
    const float4 wv = *(const float4*)(W + (size_t)(co + pc) * 128 + d0);
    Wt[d0 + 0][pc] = wv.x; Wt[d0 + 1][pc] = wv.y;
    Wt[d0 + 2][pc] = wv.z; Wt[d0 + 3][pc] = wv.w;
  }
  __syncthreads();
  const int c0 = (tid & 15) * 4, p0 = (tid >> 4) * 4;
  float acc[4][4];
#pragma unroll
  for (int i = 0; i < 4; ++i)
#pragma unroll
    for (int j = 0; j < 4; ++j) acc[i][j] = 0.0f;
#pragma unroll 4
  for (int d = 0; d < 64; ++d) {
    const float4 xa = *(const float4*)&Xt[d][p0];
    const float4 wc = *(const float4*)&Wt[d][c0];
    const float xr[4] = {xa.x, xa.y, xa.z, xa.w};
    const float wr[4] = {wc.x, wc.y, wc.z, wc.w};
#pragma unroll
    for (int i = 0; i < 4; ++i)
#pragma unroll
      for (int j = 0; j < 4; ++j) acc[i][j] = fmaf(xr[i], wr[j], acc[i][j]);
  }
#pragma unroll
  for (int i = 0; i < 4; ++i) {
    float4 o;
    o.x = acc[i][0]; o.y = acc[i][1]; o.z = acc[i][2]; o.w = acc[i][3];
    *(float4*)(Y + (size_t)(n0 + p0 + i) * 64 + c0) = o;
  }
}

// ---- gather_edge: out[n, co+c] = max_k lrelu(s*(Y[j,c] + D[n,c]) + bias) --
template <int DIN, int DS, int COUT>
__global__ __launch_bounds__(256) void gather_edge(
    const float* __restrict__ x, const float* __restrict__ Y,
    const int* __restrict__ idx, const float* __restrict__ W,
    const float* __restrict__ g, const float* __restrict__ bia,
    float* __restrict__ out, int co) {
  const int lane = threadIdx.x & 63;
  const int bid = blockIdx.x;  // 8192 = 8 x 1024
  const int wglob = ((bid & 7) << 12) + (bid >> 3) * 4 + (threadIdx.x >> 6);
  const int b = wglob >> 12;
  const int c = co + lane;

  const float* wrow = W + (size_t)c * (2 * DIN);
  const float* xi = x + (size_t)wglob * DS;
  float Dv = 0.0f;
  if constexpr (DIN == 3) {
    const float4 v = *(const float4*)xi;
    Dv = (wrow[3] - wrow[0]) * v.x + (wrow[4] - wrow[1]) * v.y +
         (wrow[5] - wrow[2]) * v.z;
  } else {
#pragma unroll
    for (int d0 = 0; d0 < DIN; d0 += 4) {
      const float4 wa4 = *(const float4*)(wrow + d0);
      const float4 wb4 = *(const float4*)(wrow + DIN + d0);
      const float4 v = *(const float4*)(xi + d0);
      Dv += (wb4.x - wa4.x) * v.x + (wb4.y - wa4.y) * v.y +
            (wb4.z - wa4.z) * v.z + (wb4.w - wa4.w) * v.w;
    }
  }
  const float invs = 1.0f / sqrtf(1.0f + 1e-5f);
  const float s = g[c] * invs;
  const float base = fmaf(s, Dv, bia[c]);

  const int* ip = idx + (size_t)wglob * KNB;
  const int jv = ip[lane < KNB ? lane : 0];
  const float* Yb = Y + (((size_t)b) << 12) * 64;
  float m = -3.0e38f;
#pragma unroll
  for (int k = 0; k < KNB; ++k) {
    const int j = __shfl(jv, k, 64);
    const float yv = Yb[(size_t)j * 64 + lane];
    float v = fmaf(s, yv, base);
    v = v > 0.0f ? v : 0.2f * v;
    m = fmaxf(m, v);
  }
  out[(size_t)wglob * COUT + c] = m;
}

// ---- split W5 [1024][320] fp32 -> hi/lo fp16 ----
__global__ __launch_bounds__(256) void splitW5(
    const float* __restrict__ W5, unsigned short* __restrict__ whi,
    unsigned short* __restrict__ wlo) {
  const int t = blockIdx.x * 256 + threadIdx.x;  // < 81920 = 1024*320/4
  const float4 v = *(const float4*)(W5 + (size_t)t * 4);
  const float vv[4] = {v.x, v.y, v.z, v.w};
  unsigned short hb[4], lb[4];
#pragma unroll
  for (int u = 0; u < 4; ++u) {
    const _Float16 h = (_Float16)vv[u];
    const _Float16 l = (_Float16)(vv[u] - (float)h);
    hb[u] = __builtin_bit_cast(unsigned short, h);
    lb[u] = __builtin_bit_cast(unsigned short, l);
  }
  *(uint2*)(whi + (size_t)t * 4) = *(uint2*)hb;
  *(uint2*)(wlo + (size_t)t * 4) = *(uint2*)lb;
}

// ---- conv5 via fp16-split MFMA: H = Xc(32768x320) @ W5^T, fused pooling --
__global__ __launch_bounds__(256) void conv5_mfma(
    const float* __restrict__ x1, const float* __restrict__ x2,
    const float* __restrict__ x3, const float* __restrict__ x4,
    const unsigned short* __restrict__ whi,
    const unsigned short* __restrict__ wlo, const float* __restrict__ g5,
    const float* __restrict__ b5, float* __restrict__ pmax,
    float* __restrict__ psum) {
  __shared__ __align__(16) unsigned short xh[64][40];
  __shared__ __align__(16) unsigned short xl[64][40];
  const int nt = blockIdx.x, ct = blockIdx.y, b = blockIdx.z;
  const int tid = threadIdx.x, wv = tid >> 6, lane = tid & 63;
  const int l15 = lane & 15, quad = lane >> 4;
  const int n0 = nt * 64, c0 = ct * 64;

  const int nl = tid >> 2;         // loader: n row 0..63
  const int kg = (tid & 3) * 8;    // loader: k group {0,8,16,24}

  f32x4 acc[4];
#pragma unroll
  for (int nj = 0; nj < 4; ++nj) acc[nj] = {0.0f, 0.0f, 0.0f, 0.0f};

  const int ca = c0 + wv * 16 + l15;  // A-frag row (c)

  for (int kt = 0; kt < 10; ++kt) {
    __syncthreads();  // prev MFMA reads done before overwrite
    const int kbase = kt * 32;
    const float* src;
    int koff;
    if (kbase < 64)       { src = x1 + ((size_t)(b * NPT + n0 + nl)) * 64;  koff = kbase; }
    else if (kbase < 128) { src = x2 + ((size_t)(b * NPT + n0 + nl)) * 64;  koff = kbase - 64; }
    else if (kbase < 192) { src = x3 + ((size_t)(b * NPT + n0 + nl)) * 64;  koff = kbase - 128; }
    else                  { src = x4 + ((size_t)(b * NPT + n0 + nl)) * 128; koff = kbase - 192; }
    const float4 v0 = *(const float4*)(src + koff + kg);
    const float4 v1 = *(const float4*)(src + koff + kg + 4);
    const float vv[8] = {v0.x, v0.y, v0.z, v0.w, v1.x, v1.y, v1.z, v1.w};
    unsigned short hb[8], lb[8];
#pragma unroll
    for (int u = 0; u < 8; ++u) {
      const _Float16 h = (_Float16)vv[u];
      const _Float16 l = (_Float16)(vv[u] - (float)h);
      hb[u] = __builtin_bit_cast(unsigned short, h);
      lb[u] = __builtin_bit_cast(unsigned short, l);
    }
    *(uint4*)&xh[nl][kg] = *(uint4*)hb;
    *(uint4*)&xl[nl][kg] = *(uint4*)lb;
    __syncthreads();
    const half8 wh =
        *(const half8*)(whi + (size_t)ca * 320 + kbase + quad * 8);
    const half8 wl =
        *(const half8*)(wlo + (size_t)ca * 320 + kbase + quad * 8);
#pragma unroll
    for (int nj = 0; nj < 4; ++nj) {
      const half8 bh = *(const half8*)&xh[nj * 16 + l15][quad * 8];
      const half8 bl = *(const half8*)&xl[nj * 16 + l15][quad * 8];
      f32x4 a = acc[nj];
      a = __builtin_amdgcn_mfma_f32_16x16x32_f16(wl, bh, a, 0, 0, 0);
      a = __builtin_amdgcn_mfma_f32_16x16x32_f16(wh, bl, a, 0, 0, 0);
      a = __builtin_amdgcn_mfma_f32_16x16x32_f16(wh, bh, a, 0, 0, 0);
      acc[nj] = a;
    }
  }

  const float invs = 1.0f / sqrtf(1.0f + 1e-5f);
#pragma unroll
  for (int r = 0; r < 4; ++r) {
    const int c = c0 + wv * 16 + quad * 4 + r;
    const float s = g5[c] * invs;
    const float bb = b5[c];
    float mx = -3.0e38f, sm = 0.0f;
#pragma unroll
    for (int nj = 0; nj < 4; ++nj) {
      float v = fmaf(s, acc[nj][r], bb);
      v = v > 0.0f ? v : 0.2f * v;
      mx = fmaxf(mx, v);
      sm += v;
    }
#pragma unroll
    for (int d = 1; d < 16; d <<= 1) {
      mx = fmaxf(mx, __shfl_xor(mx, d, 64));
      sm += __shfl_xor(sm, d, 64);
    }
    if (l15 == 0) {
      pmax[((size_t)b * 1024 + c) * 64 + nt] = mx;
      psum[((size_t)b * 1024 + c) * 64 + nt] = sm;
    }
  }
}

// ---- reduce partials -> gfeat [B][2048] = [gmax | gavg] ----
__global__ __launch_bounds__(256) void reduce5(const float* __restrict__ pmax,
                                               const float* __restrict__ psum,
                                               float* __restrict__ gfeat) {
  const int t = blockIdx.x * 256 + threadIdx.x;  // < 8192 = B*1024
  const int b = t >> 10, c = t & 1023;
  const float* pm = pmax + (size_t)t * 64;
  const float* ps = psum + (size_t)t * 64;
  float mx = -3.0e38f, sm = 0.0f;
  for (int i = 0; i < 64; i += 4) {
    const float4 v = *(const float4*)(pm + i);
    mx = fmaxf(mx, fmaxf(fmaxf(v.x, v.y), fmaxf(v.z, v.w)));
    const float4 u = *(const float4*)(ps + i);
    sm += (u.x + u.y) + (u.z + u.w);
  }
  gfeat[b * 2048 + c] = mx;
  gfeat[b * 2048 + 1024 + c] = sm * (1.0f / 4096.0f);
}

// ---- head: y1 = lrelu(bn(gfeat @ Wl1^T)) ----
__global__ __launch_bounds__(256) void head1(const float* __restrict__ gfeat,
                                             const float* __restrict__ Wl1,
                                             const float* __restrict__ g6,
                                             const float* __restrict__ b6,
                                             float* __restrict__ y1g) {
  __shared__ float gf[2048];
  __shared__ float red[256];
  const int tid = threadIdx.x;
  const int cb = blockIdx.x, b = blockIdx.y;
  const float4* gsrc = (const float4*)(gfeat + b * 2048);
  for (int p = tid; p < 512; p += 256) ((float4*)gf)[p] = gsrc[p];
  __syncthreads();
  const int cl = cb * 64 + (tid >> 2);
  const int q = tid & 3;
  const float* wr = Wl1 + (size_t)cl * 2048 + q * 512;
  const float* gq = gf + q * 512;
  float acc = 0.0f;
  for (int k0 = 0; k0 < 512; k0 += 8) {
    const float4 w0 = *(const float4*)(wr + k0);
    const float4 w1 = *(const float4*)(wr + k0 + 4);
    acc = fmaf(w0.x, gq[k0 + 0], acc); acc = fmaf(w0.y, gq[k0 + 1], acc);
    acc = fmaf(w0.z, gq[k0 + 2], acc); acc = fmaf(w0.w, gq[k0 + 3], acc);
    acc = fmaf(w1.x, gq[k0 + 4], acc); acc = fmaf(w1.y, gq[k0 + 5], acc);
    acc = fmaf(w1.z, gq[k0 + 6], acc); acc = fmaf(w1.w, gq[k0 + 7], acc);
  }
  red[tid] = acc;
  __syncthreads();
  if (q == 0) {
    float v = red[tid] + red[tid + 1] + red[tid + 2] + red[tid + 3];
    const float invs = 1.0f / sqrtf(1.0f + 1e-5f);
    v = fmaf(g6[cl] * invs, v, b6[cl]);
    v = v > 0.0f ? v : 0.2f * v;
    y1g[b * 512 + cl] = v;
  }
}

// ---- head: y2, y3, broadcast to [B][N][5] fp32 ----
__global__ __launch_bounds__(256) void head2(
    const float* __restrict__ y1g, const float* __restrict__ Wl2,
    const float* __restrict__ bl2, const float* __restrict__ g7,
    const float* __restrict__ b7, const float* __restrict__ Wl3,
    const float* __restrict__ bl3, float* __restrict__ out) {
  __shared__ float y1s[512];
  __shared__ float y2s[256];
  __shared__ float y3s[5];
  const int b = blockIdx.x;
  const int t = threadIdx.x;
  y1s[t] = y1g[b * 512 + t];
  y1s[t + 256] = y1g[b * 512 + t + 256];
  __syncthreads();
  {
    const float* wr = Wl2 + (size_t)t * 512;
    float acc = 0.0f;
    for (int k0 = 0; k0 < 512; k0 += 8) {
      const float4 w0 = *(const float4*)(wr + k0);
      const float4 w1 = *(const float4*)(wr + k0 + 4);
      acc = fmaf(w0.x, y1s[k0 + 0], acc); acc = fmaf(w0.y, y1s[k0 + 1], acc);
      acc = fmaf(w0.z, y1s[k0 + 2], acc); acc = fmaf(w0.w, y1s[k0 + 3], acc);
      acc = fmaf(w1.x, y1s[k0 + 4], acc); acc = fmaf(w1.y, y1s[k0 + 5], acc);
      acc = fmaf(w1.z, y1s[k0 + 6], acc); acc = fmaf(w1.w, y1s[k0 + 7], acc);
    }
    const float invs = 1.0f / sqrtf(1.0f + 1e-5f);
    float v = acc + bl2[t];
    v = fmaf(g7[t] * invs, v, b7[t]);
    v = v > 0.0f ? v : 0.2f * v;
    y2s[t] = v;
  }
  __syncthreads();
  if (t < 5) {
    const float* wr = Wl3 + (size_t)t * 256;
    float acc = 0.0f;
    for (int k = 0; k < 256; ++k) acc += wr[k] * y2s[k];
    y3s[t] = acc + bl3[t];
  }
  __syncthreads();
  for (int e = t; e < NPT * 5; e += 256)
    out[(size_t)b * (NPT * 5) + e] = y3s[e % 5];
}

extern "C" void kernel_launch(void* const* d_in, const int* in_sizes, int n_in,
                              void* d_out, int out_size, void* d_ws, size_t ws_size,
                              hipStream_t stream) {
  (void)in_sizes; (void)n_in; (void)out_size;
  const float* xyz = (const float*)d_in[0];
  const float* W1  = (const float*)d_in[1];
  const float* g1  = (const float*)d_in[2];
  const float* b1  = (const float*)d_in[3];
  const float* W2  = (const float*)d_in[4];
  const float* g2  = (const float*)d_in[5];
  const float* b2  = (const float*)d_in[6];
  const float* W3  = (const float*)d_in[7];
  const float* g3  = (const float*)d_in[8];
  const float* b3  = (const float*)d_in[9];
  const float* W4  = (const float*)d_in[10];
  const float* g4  = (const float*)d_in[11];
  const float* b4  = (const float*)d_in[12];
  const float* W5  = (const float*)d_in[13];
  const float* g5  = (const float*)d_in[14];
  const float* b5  = (const float*)d_in[15];
  const float* Wl1 = (const float*)d_in[16];
  const float* g6  = (const float*)d_in[17];
  const float* b6  = (const float*)d_in[18];
  const float* Wl2 = (const float*)d_in[19];
  const float* bl2 = (const float*)d_in[20];
  const float* g7  = (const float*)d_in[21];
  const float* b7  = (const float*)d_in[22];
  const float* Wl3 = (const float*)d_in[23];
  const float* bl3 = (const float*)d_in[24];

  char* ws = (char*)d_ws;
  float* x0    = (float*)(ws + 0);         //  524288 B
  float* x1    = (float*)(ws + 524288);    // 8388608 B
  float* x2    = (float*)(ws + 8912896);   // 8388608 B
  float* x3    = (float*)(ws + 17301504);  // 8388608 B
  float* x4    = (float*)(ws + 25690112);  // 16777216 B
  float* sqb   = (float*)(ws + 42467328);  //  131072 B
  int*   idxb  = (int*)  (ws + 42598400);  // 2621440 B
  float* pmx   = (float*)(ws + 45219840);  // 4194304 B (arena)
  float* psm   = (float*)(ws + 49414144);  // 4194304 B (arena)
  float* gfeat = (float*)(ws + 53608448);  //   65536 B
  float* y1g   = (float*)(ws + 53673984);  //   16384 B
  if (ws_size < 53690368) return;          // need ~51.2 MB scratch

  // arena (pmx..psm, 8 MB) time-shared: xhi/xlo during knn, Y during
  // featg/gather, pmax/psum partials during conv5/reduce5. idxb region
  // time-shared: neighbor indices during knn/gather, W5 hi/lo during conv5.
  unsigned short* xhi = (unsigned short*)pmx;
  unsigned short* xlo = (unsigned short*)psm;
  float* Yb = pmx;  // 8 MB: [32768][64] fp32
  unsigned short* whi = (unsigned short*)idxb;            // 655360 B
  unsigned short* wlo = (unsigned short*)idxb + 327680;   // 655360 B

  cvt_xyz<<<128, 256, 0, stream>>>(xyz, x0);

  knn3<<<512, 256, 59392, stream>>>(x0, idxb);
  featg3<<<2048, 256, 0, stream>>>(x0, W1, Yb);
  gather_edge<3, 4, 64><<<8192, 256, 0, stream>>>(x0, Yb, idxb, W1, g1, b1, x1, 0);

  sqsplit<<<512, 256, 0, stream>>>(x1, sqb, xhi, xlo);
  knn_mfma<<<512, 256, 59392, stream>>>(xhi, xlo, sqb, idxb);
  featg64<<<512, 256, 0, stream>>>(x1, W2, 0, Yb);
  gather_edge<64, 64, 64><<<8192, 256, 0, stream>>>(x1, Yb, idxb, W2, g2, b2, x2, 0);

  sqsplit<<<512, 256, 0, stream>>>(x2, sqb, xhi, xlo);
  knn_mfma<<<512, 256, 59392, stream>>>(xhi, xlo, sqb, idxb);
  featg64<<<512, 256, 0, stream>>>(x2, W3, 0, Yb);
  gather_edge<64, 64, 64><<<8192, 256, 0, stream>>>(x2, Yb, idxb, W3, g3, b3, x3, 0);

  sqsplit<<<512, 256, 0, stream>>>(x3, sqb, xhi, xlo);
  knn_mfma<<<512, 256, 59392, stream>>>(xhi, xlo, sqb, idxb);
  featg64<<<512, 256, 0, stream>>>(x3, W4, 0, Yb);
  gather_edge<64, 64, 128><<<8192, 256, 0, stream>>>(x3, Yb, idxb, W4, g4, b4, x4, 0);
  featg64<<<512, 256, 0, stream>>>(x3, W4, 64, Yb);
  gather_edge<64, 64, 128><<<8192, 256, 0, stream>>>(x3, Yb, idxb, W4, g4, b4, x4, 64);

  splitW5<<<320, 256, 0, stream>>>(W5, whi, wlo);
  conv5_mfma<<<dim3(64, 16, 8), 256, 0, stream>>>(x1, x2, x3, x4, whi, wlo,
                                                  g5, b5, pmx, psm);
  reduce5<<<32, 256, 0, stream>>>(pmx, psm, gfeat);
  head1<<<dim3(8, 8), 256, 0, stream>>>(gfeat, Wl1, g6, b6, y1g);
  head2<<<8, 256, 0, stream>>>(y1g, Wl2, bl2, g7, b7, Wl3, bl3, (float*)d_out);
}

// Round 13
// 2032.814 us; speedup vs baseline: 1.3309x; 1.3309x over previous
//
#include <hip/hip_runtime.h>

// DGCNN inference, MI355X gfx950. B=8, N=4096, K=20. fp32 in/out.
// FINAL consolidation build (best measured: 2033 us): r6-verbatim knn
// (full j-scan, 16 rows/wave, CAP=128, register prefetch dbuf) + r8
// conv5 fp16 hi/lo split MFMA + fused pooling. EdgeConv factored
// (featg + gather-max), XCD-pinned batches throughout.

constexpr int NB  = 8;
constexpr int NPT = 4096;
constexpr int KNB = 20;
constexpr int CAP = 128;  // candidate buffer entries per row

typedef _Float16 half8 __attribute__((ext_vector_type(8)));
typedef float f32x4 __attribute__((ext_vector_type(4)));

// monotone float->uint map (order-preserving, handles negatives)
__device__ __forceinline__ unsigned int fmono(float f) {
  unsigned int u = __float_as_uint(f);
  return u ^ ((unsigned int)(((int)u) >> 31) | 0x80000000u);
}

// ---- full-wave bitonic: 64 smallest of buf[row][0..n), n <= 128, asc ----
// Lanes 0..63 end ascending; top-20 in lanes 0..19. u64 [64 rows][CAP].
__device__ __attribute__((noinline)) unsigned long long compact_row(
    int row, int n, int lane) {
  extern __shared__ char smem[];
  unsigned long long* buf = (unsigned long long*)smem + (size_t)row * CAP;
  const unsigned long long INFK = ~0ull;
  unsigned long long a = (lane < n) ? buf[lane] : INFK;
  unsigned long long c = (lane + 64 < n) ? buf[lane + 64] : INFK;
#pragma unroll
  for (int k = 2; k <= 64; k <<= 1) {
#pragma unroll
    for (int j = k >> 1; j > 0; j >>= 1) {
      const bool tm = (((lane & k) == 0) == ((lane & j) == 0));
      const unsigned long long oa = __shfl_xor(a, j, 64);
      a = ((a < oa) == tm) ? a : oa;  // ascending network
      const unsigned long long oc = __shfl_xor(c, j, 64);
      c = ((c < oc) == tm) ? oc : c;  // inverted -> descending
    }
  }
  unsigned long long m = a < c ? a : c;  // 64 smallest (bitonic)
#pragma unroll
  for (int j = 32; j > 0; j >>= 1) {  // merge to ascending
    const unsigned long long o = __shfl_xor(m, j, 64);
    const bool low = (lane & j) == 0;
    m = ((m < o) == low) ? m : o;
  }
  return m;
}

// ---- branch-free filter+append for 4 keys x 4 rows (one row per quad) ----
// base_r = w*16 + r; my quad's row = base_r + quad*4. tau/cnt in registers,
// quad-uniform. One uniform skip branch; compaction path is rare (exact).
__device__ __forceinline__ void sel4(unsigned long long k0,
                                     unsigned long long k1,
                                     unsigned long long k2,
                                     unsigned long long k3, int base_r,
                                     int quad, int lane, unsigned int below,
                                     unsigned long long& tau, int& cnt) {
  extern __shared__ char smem[];
  unsigned long long* bufB = (unsigned long long*)smem;
#pragma unroll 1
  for (int attempt = 0; attempt < 2; ++attempt) {
    const unsigned long long m0 = __ballot(k0 < tau);
    const unsigned long long m1 = __ballot(k1 < tau);
    const unsigned long long m2 = __ballot(k2 < tau);
    const unsigned long long m3 = __ballot(k3 < tau);
    if ((m0 | m1 | m2 | m3) == 0ull) return;  // uniform: nothing anywhere
    const int sh = quad * 16;
    const unsigned int s0 = (unsigned int)(m0 >> sh) & 0xFFFFu;
    const unsigned int s1 = (unsigned int)(m1 >> sh) & 0xFFFFu;
    const unsigned int s2 = (unsigned int)(m2 >> sh) & 0xFFFFu;
    const unsigned int s3 = (unsigned int)(m3 >> sh) & 0xFFFFu;
    const int tot = __popc(s0) + __popc(s1) + __popc(s2) + __popc(s3);
    const unsigned long long needm = __ballot(cnt + tot > CAP);
    if (needm != 0ull && attempt == 0) {  // rare: compact overflowing rows
#pragma unroll 1
      for (int q = 0; q < 4; ++q) {
        if ((needm >> (q * 16)) & 1ull) {
          const int nq = __shfl(cnt, q * 16, 64);
          const unsigned long long sv = compact_row(base_r + q * 4, nq, lane);
          const unsigned long long t19 = __shfl(sv, 19, 64);
          if (lane < 20) bufB[(size_t)(base_r + q * 4) * CAP + lane] = sv;
          if (quad == q) { tau = t19; cnt = 20; }
        }
      }
      continue;  // retry with tightened tau (guaranteed fit)
    }
    int pos = cnt + __popc(s0 & below) + __popc(s1 & below) +
              __popc(s2 & below) + __popc(s3 & below);
    unsigned long long* bp = bufB + (size_t)(base_r + quad * 4) * CAP;
    if (k0 < tau) { bp[pos] = k0; ++pos; }
    if (k1 < tau) { bp[pos] = k1; ++pos; }
    if (k2 < tau) { bp[pos] = k2; ++pos; }
    if (k3 < tau) { bp[pos] = k3; }
    cnt += tot;
    return;
  }
}

// ---- convert xyz fp32 [B][N][3] -> fp32 [B][N][4] (pad 0) ----
__global__ __launch_bounds__(256) void cvt_xyz(const float* __restrict__ xyz,
                                               float* __restrict__ x0) {
  const int t = blockIdx.x * 256 + threadIdx.x;  // < B*N
  float4 v;
  v.x = xyz[t * 3 + 0];
  v.y = xyz[t * 3 + 1];
  v.z = xyz[t * 3 + 2];
  v.w = 0.0f;
  *(float4*)(x0 + (size_t)t * 4) = v;
}

// ---- sq norms + fp16 hi/lo split of a [B*N][64] fp32 feature map ----
__global__ __launch_bounds__(256) void sqsplit(const float* __restrict__ x,
                                               float* __restrict__ sqo,
                                               unsigned short* __restrict__ xhi,
                                               unsigned short* __restrict__ xlo) {
  const int t = blockIdx.x * 256 + threadIdx.x;  // < B*N*4
  const int p = t >> 2, c = t & 3;
  const float* src = x + (size_t)p * 64 + c * 16;
  float s = 0.0f;
  unsigned short hb[16], lb[16];
#pragma unroll
  for (int e = 0; e < 16; e += 4) {
    const float4 v = *(const float4*)(src + e);
    const float vv[4] = {v.x, v.y, v.z, v.w};
#pragma unroll
    for (int u = 0; u < 4; ++u) {
      const float f = vv[u];
      s = fmaf(f, f, s);
      const _Float16 h = (_Float16)f;
      const _Float16 l = (_Float16)(f - (float)h);
      hb[e + u] = __builtin_bit_cast(unsigned short, h);
      lb[e + u] = __builtin_bit_cast(unsigned short, l);
    }
  }
  unsigned short* dh = xhi + (size_t)p * 64 + c * 16;
  unsigned short* dl = xlo + (size_t)p * 64 + c * 16;
  *(uint4*)dh = *(uint4*)hb;
  *(uint4*)(dh + 8) = *(uint4*)(hb + 8);
  *(uint4*)dl = *(uint4*)lb;
  *(uint4*)(dl + 8) = *(uint4*)(lb + 8);
  s += __shfl_xor(s, 1, 64);
  s += __shfl_xor(s, 2, 64);
  if (c == 0) sqo[p] = s;
}

// ---- knn layer 1 (D=3): direct distances, xj register double-buffer ----
// Grid 512: b = bid&7 (XCD pin), i0 = (bid>>3)*64. dyn LDS 65536 B.
__global__ __launch_bounds__(256, 2) void knn3(const float* __restrict__ x0,
                                               int* __restrict__ idxout) {
  const int bid = blockIdx.x;
  const int b = bid & 7;
  const int i0 = (bid >> 3) * 64;
  const int tid = threadIdx.x, w = tid >> 6, lane = tid & 63;
  const int l15 = lane & 15, quad = lane >> 4;
  const unsigned int below = (1u << l15) - 1u;
  const float* xb = x0 + (size_t)b * (NPT * 4);

  float xix[4], xiy[4], xiz[4];
#pragma unroll
  for (int r = 0; r < 4; ++r) {
    const float4 v =
        *(const float4*)(xb + (size_t)(i0 + w * 16 + quad * 4 + r) * 4);
    xix[r] = v.x;
    xiy[r] = v.y;
    xiz[r] = v.z;
  }

  unsigned long long tau[4] = {~0ull, ~0ull, ~0ull, ~0ull};
  int cnt[4] = {0, 0, 0, 0};

  float4 cj[4];
#pragma unroll
  for (int nj = 0; nj < 4; ++nj)
    cj[nj] = *(const float4*)(xb + (size_t)(nj * 16 + l15) * 4);

  for (int jt = 0; jt < NPT / 64; ++jt) {
    const int j0 = jt * 64;
    // prefetch next tile (overlaps with the sel phase below)
    float4 nj4[4];
    {
      const int jn0 = (jt + 1 < NPT / 64 ? jt + 1 : jt) * 64;
#pragma unroll
      for (int nj = 0; nj < 4; ++nj)
        nj4[nj] = *(const float4*)(xb + (size_t)(jn0 + nj * 16 + l15) * 4);
    }
#pragma unroll
    for (int r = 0; r < 4; ++r) {
      unsigned long long k[4];
#pragma unroll
      for (int nj = 0; nj < 4; ++nj) {
        const float dx = cj[nj].x - xix[r];
        const float dy = cj[nj].y - xiy[r];
        const float dz = cj[nj].z - xiz[r];
        const float dd = fmaf(dx, dx, fmaf(dy, dy, dz * dz));
        k[nj] = ((unsigned long long)fmono(dd) << 32) |
                (unsigned int)(j0 + nj * 16 + l15);
      }
      sel4(k[0], k[1], k[2], k[3], w * 16 + r, quad, lane, below, tau[r],
           cnt[r]);
    }
#pragma unroll
    for (int nj = 0; nj < 4; ++nj) cj[nj] = nj4[nj];
  }
#pragma unroll 1
  for (int rw = 0; rw < 16; ++rw) {
    const int q = rw >> 2, r = rw & 3;
    const int nq = __shfl(cnt[r], q * 16, 64);
    const unsigned long long sv = compact_row(w * 16 + rw, nq, lane);
    const int i = i0 + w * 16 + rw;
    if (lane < 20)
      idxout[((size_t)(b * NPT + i)) * KNB + lane] = (int)(unsigned int)sv;
  }
}

// ---- knn layers 2-4 (D=64): fp16x2-split MFMA, B-frag double-buffer ----
// Grid 512: b = bid&7 (XCD pin -> 2MB/batch L2-resident). dyn LDS 65536 B.
__global__ __launch_bounds__(256, 2) void knn_mfma(
    const unsigned short* __restrict__ xhi16,
    const unsigned short* __restrict__ xlo16,
    const float* __restrict__ sqn, int* __restrict__ idxout) {
  const int bid = blockIdx.x;
  const int b = bid & 7;
  const int i0 = (bid >> 3) * 64;
  const int tid = threadIdx.x, w = tid >> 6, lane = tid & 63;
  const int l15 = lane & 15, quad = lane >> 4;
  const unsigned int below = (1u << l15) - 1u;

  const half8* Hb = (const half8*)(xhi16 + (size_t)b * NPT * 64);
  const half8* Lb = (const half8*)(xlo16 + (size_t)b * NPT * 64);
  const float* sqb = sqn + b * NPT;

  const int ia = i0 + w * 16 + l15;
  const half8 ah0 = Hb[(size_t)ia * 8 + quad];
  const half8 ah1 = Hb[(size_t)ia * 8 + 4 + quad];
  const half8 al0 = Lb[(size_t)ia * 8 + quad];
  const half8 al1 = Lb[(size_t)ia * 8 + 4 + quad];

  unsigned long long tau[4] = {~0ull, ~0ull, ~0ull, ~0ull};
  int cnt[4] = {0, 0, 0, 0};

  // B-fragment double buffer: cb = current tile, loaded for jt=0 here
  half8 cb[16];
  float sqc[4];
#pragma unroll
  for (int nj = 0; nj < 4; ++nj) {
    const int jb = nj * 16 + l15;
    cb[nj * 4 + 0] = Hb[(size_t)jb * 8 + quad];
    cb[nj * 4 + 1] = Hb[(size_t)jb * 8 + 4 + quad];
    cb[nj * 4 + 2] = Lb[(size_t)jb * 8 + quad];
    cb[nj * 4 + 3] = Lb[(size_t)jb * 8 + 4 + quad];
    sqc[nj] = sqb[nj * 16 + l15];
  }

  for (int jt = 0; jt < NPT / 64; ++jt) {
    const int j0 = jt * 64;
    // issue next-tile loads first: latency hides under MFMA + sel below
    half8 nb[16];
    float sqn4[4];
    {
      const int jn0 = (jt + 1 < NPT / 64 ? jt + 1 : jt) * 64;
#pragma unroll
      for (int nj = 0; nj < 4; ++nj) {
        const int jb = jn0 + nj * 16 + l15;
        nb[nj * 4 + 0] = Hb[(size_t)jb * 8 + quad];
        nb[nj * 4 + 1] = Hb[(size_t)jb * 8 + 4 + quad];
        nb[nj * 4 + 2] = Lb[(size_t)jb * 8 + quad];
        nb[nj * 4 + 3] = Lb[(size_t)jb * 8 + 4 + quad];
        sqn4[nj] = sqb[jn0 + nj * 16 + l15];
      }
    }
    f32x4 acc[4];
#pragma unroll
    for (int nj = 0; nj < 4; ++nj) {
      f32x4 a = {0.0f, 0.0f, 0.0f, 0.0f};
      a = __builtin_amdgcn_mfma_f32_16x16x32_f16(al0, cb[nj * 4 + 0], a, 0, 0, 0);
      a = __builtin_amdgcn_mfma_f32_16x16x32_f16(al1, cb[nj * 4 + 1], a, 0, 0, 0);
      a = __builtin_amdgcn_mfma_f32_16x16x32_f16(ah0, cb[nj * 4 + 2], a, 0, 0, 0);
      a = __builtin_amdgcn_mfma_f32_16x16x32_f16(ah1, cb[nj * 4 + 3], a, 0, 0, 0);
      a = __builtin_amdgcn_mfma_f32_16x16x32_f16(ah0, cb[nj * 4 + 0], a, 0, 0, 0);
      a = __builtin_amdgcn_mfma_f32_16x16x32_f16(ah1, cb[nj * 4 + 1], a, 0, 0, 0);
      acc[nj] = a;
    }
    // C layout: row = quad*4+r, col = nj*16+l15
#pragma unroll
    for (int r = 0; r < 4; ++r) {
      unsigned long long k[4];
#pragma unroll
      for (int nj = 0; nj < 4; ++nj) {
        const float dd = fmaf(-2.0f, acc[nj][r], sqc[nj]);
        k[nj] = ((unsigned long long)fmono(dd) << 32) |
                (unsigned int)(j0 + nj * 16 + l15);
      }
      sel4(k[0], k[1], k[2], k[3], w * 16 + r, quad, lane, below, tau[r],
           cnt[r]);
    }
#pragma unroll
    for (int e = 0; e < 16; ++e) cb[e] = nb[e];
#pragma unroll
    for (int nj = 0; nj < 4; ++nj) sqc[nj] = sqn4[nj];
  }
#pragma unroll 1
  for (int rw = 0; rw < 16; ++rw) {
    const int q = rw >> 2, r = rw & 3;
    const int nq = __shfl(cnt[r], q * 16, 64);
    const unsigned long long sv = compact_row(w * 16 + rw, nq, lane);
    const int i = i0 + w * 16 + rw;
    if (lane < 20)
      idxout[((size_t)(b * NPT + i)) * KNB + lane] = (int)(unsigned int)sv;
  }
}

// ---- featg3: Y[p, c] = wa_c . x0[p]  (DIN=3), XCD-pinned ----
__global__ __launch_bounds__(256) void featg3(const float* __restrict__ x0,
                                              const float* __restrict__ W,
                                              float* __restrict__ Y) {
  const int lane = threadIdx.x & 63;
  const int bid = blockIdx.x;  // 2048 = 8 x 256
  const int p0 =
      ((bid & 7) << 12) + ((bid >> 3) * 4 + (threadIdx.x >> 6)) * 4;
  const float* wr = W + lane * 6;
  const float w0 = wr[0], w1 = wr[1], w2 = wr[2];
#pragma unroll
  for (int r = 0; r < 4; ++r) {
    const float4 v = *(const float4*)(x0 + (size_t)(p0 + r) * 4);
    Y[(size_t)(p0 + r) * 64 + lane] = w0 * v.x + w1 * v.y + w2 * v.z;
  }
}

// ---- featg64: Y[p, c'] = sum_d X[p][d] * W[(co+c')][d], XCD-pinned ----
__global__ __launch_bounds__(256) void featg64(const float* __restrict__ X,
                                               const float* __restrict__ W,
                                               int co, float* __restrict__ Y) {
  __shared__ float Xt[64][68];  // [d][p]
  __shared__ float Wt[64][68];  // [d][c]
  const int tid = threadIdx.x;
  const int bid = blockIdx.x;  // 512 = 8 x 64
  const int n0 = ((bid & 7) << 12) + (bid >> 3) * 64;
  const int pc = tid & 63, dg = tid >> 6;  // dg 0..3
#pragma unroll
  for (int rep = 0; rep < 4; ++rep) {
    const int d0 = dg * 16 + rep * 4;
    const float4 xv = *(const float4*)(X + (size_t)(n0 + pc) * 64 + d0);
    Xt[d0 + 0][pc] = xv.x; Xt[d0 + 1][pc] = xv.y;
    Xt[d0 + 2][pc] = xv.z; Xt[d0 + 3][pc] = xv.w;
    const float4 wv = *(const float4*)(W + (size_t)(co + pc) * 128 + d0);
    Wt[d0 + 0][pc] = wv.x; Wt[d0 + 1][pc] = wv.y;
    Wt[d0 + 2][pc] = wv.z; Wt[d0 + 3][pc] = wv.w;
  }
  __syncthreads();
  const int c0 = (tid & 15) * 4, p0 = (tid >> 4) * 4;
  float acc[4][4];
#pragma unroll
  for (int i = 0; i < 4; ++i)
#pragma unroll
    for (int j = 0; j < 4; ++j) acc[i][j] = 0.0f;
#pragma unroll 4
  for (int d = 0; d < 64; ++d) {
    const float4 xa = *(const float4*)&Xt[d][p0];
    const float4 wc = *(const float4*)&Wt[d][c0];
    const float xr[4] = {xa.x, xa.y, xa.z, xa.w};
    const float wr[4] = {wc.x, wc.y, wc.z, wc.w};
#pragma unroll
    for (int i = 0; i < 4; ++i)
#pragma unroll
      for (int j = 0; j < 4; ++j) acc[i][j] = fmaf(xr[i], wr[j], acc[i][j]);
  }
#pragma unroll
  for (int i = 0; i < 4; ++i) {
    float4 o;
    o.x = acc[i][0]; o.y = acc[i][1]; o.z = acc[i][2]; o.w = acc[i][3];
    *(float4*)(Y + (size_t)(n0 + p0 + i) * 64 + c0) = o;
  }
}

// ---- gather_edge: out[n, co+c] = max_k lrelu(s*(Y[j,c] + D[n,c]) + bias) --
template <int DIN, int DS, int COUT>
__global__ __launch_bounds__(256) void gather_edge(
    const float* __restrict__ x, const float* __restrict__ Y,
    const int* __restrict__ idx, const float* __restrict__ W,
    const float* __restrict__ g, const float* __restrict__ bia,
    float* __restrict__ out, int co) {
  const int lane = threadIdx.x & 63;
  const int bid = blockIdx.x;  // 8192 = 8 x 1024
  const int wglob = ((bid & 7) << 12) + (bid >> 3) * 4 + (threadIdx.x >> 6);
  const int b = wglob >> 12;
  const int c = co + lane;

  const float* wrow = W + (size_t)c * (2 * DIN);
  const float* xi = x + (size_t)wglob * DS;
  float Dv = 0.0f;
  if constexpr (DIN == 3) {
    const float4 v = *(const float4*)xi;
    Dv = (wrow[3] - wrow[0]) * v.x + (wrow[4] - wrow[1]) * v.y +
         (wrow[5] - wrow[2]) * v.z;
  } else {
#pragma unroll
    for (int d0 = 0; d0 < DIN; d0 += 4) {
      const float4 wa4 = *(const float4*)(wrow + d0);
      const float4 wb4 = *(const float4*)(wrow + DIN + d0);
      const float4 v = *(const float4*)(xi + d0);
      Dv += (wb4.x - wa4.x) * v.x + (wb4.y - wa4.y) * v.y +
            (wb4.z - wa4.z) * v.z + (wb4.w - wa4.w) * v.w;
    }
  }
  const float invs = 1.0f / sqrtf(1.0f + 1e-5f);
  const float s = g[c] * invs;
  const float base = fmaf(s, Dv, bia[c]);

  const int* ip = idx + (size_t)wglob * KNB;
  const int jv = ip[lane < KNB ? lane : 0];
  const float* Yb = Y + (((size_t)b) << 12) * 64;
  float m = -3.0e38f;
#pragma unroll
  for (int k = 0; k < KNB; ++k) {
    const int j = __shfl(jv, k, 64);
    const float yv = Yb[(size_t)j * 64 + lane];
    float v = fmaf(s, yv, base);
    v = v > 0.0f ? v : 0.2f * v;
    m = fmaxf(m, v);
  }
  out[(size_t)wglob * COUT + c] = m;
}

// ---- split W5 [1024][320] fp32 -> hi/lo fp16 ----
__global__ __launch_bounds__(256) void splitW5(
    const float* __restrict__ W5, unsigned short* __restrict__ whi,
    unsigned short* __restrict__ wlo) {
  const int t = blockIdx.x * 256 + threadIdx.x;  // < 81920 = 1024*320/4
  const float4 v = *(const float4*)(W5 + (size_t)t * 4);
  const float vv[4] = {v.x, v.y, v.z, v.w};
  unsigned short hb[4], lb[4];
#pragma unroll
  for (int u = 0; u < 4; ++u) {
    const _Float16 h = (_Float16)vv[u];
    const _Float16 l = (_Float16)(vv[u] - (float)h);
    hb[u] = __builtin_bit_cast(unsigned short, h);
    lb[u] = __builtin_bit_cast(unsigned short, l);
  }
  *(uint2*)(whi + (size_t)t * 4) = *(uint2*)hb;
  *(uint2*)(wlo + (size_t)t * 4) = *(uint2*)lb;
}

// ---- conv5 via fp16-split MFMA: H = Xc(32768x320) @ W5^T, fused pooling --
__global__ __launch_bounds__(256) void conv5_mfma(
    const float* __restrict__ x1, const float* __restrict__ x2,
    const float* __restrict__ x3, const float* __restrict__ x4,
    const unsigned short* __restrict__ whi,
    const unsigned short* __restrict__ wlo, const float* __restrict__ g5,
    const float* __restrict__ b5, float* __restrict__ pmax,
    float* __restrict__ psum) {
  __shared__ __align__(16) unsigned short xh[64][40];
  __shared__ __align__(16) unsigned short xl[64][40];
  const int nt = blockIdx.x, ct = blockIdx.y, b = blockIdx.z;
  const int tid = threadIdx.x, wv = tid >> 6, lane = tid & 63;
  const int l15 = lane & 15, quad = lane >> 4;
  const int n0 = nt * 64, c0 = ct * 64;

  const int nl = tid >> 2;         // loader: n row 0..63
  const int kg = (tid & 3) * 8;    // loader: k group {0,8,16,24}

  f32x4 acc[4];
#pragma unroll
  for (int nj = 0; nj < 4; ++nj) acc[nj] = {0.0f, 0.0f, 0.0f, 0.0f};

  const int ca = c0 + wv * 16 + l15;  // A-frag row (c)

  for (int kt = 0; kt < 10; ++kt) {
    __syncthreads();  // prev MFMA reads done before overwrite
    const int kbase = kt * 32;
    const float* src;
    int koff;
    if (kbase < 64)       { src = x1 + ((size_t)(b * NPT + n0 + nl)) * 64;  koff = kbase; }
    else if (kbase < 128) { src = x2 + ((size_t)(b * NPT + n0 + nl)) * 64;  koff = kbase - 64; }
    else if (kbase < 192) { src = x3 + ((size_t)(b * NPT + n0 + nl)) * 64;  koff = kbase - 128; }
    else                  { src = x4 + ((size_t)(b * NPT + n0 + nl)) * 128; koff = kbase - 192; }
    const float4 v0 = *(const float4*)(src + koff + kg);
    const float4 v1 = *(const float4*)(src + koff + kg + 4);
    const float vv[8] = {v0.x, v0.y, v0.z, v0.w, v1.x, v1.y, v1.z, v1.w};
    unsigned short hb[8], lb[8];
#pragma unroll
    for (int u = 0; u < 8; ++u) {
      const _Float16 h = (_Float16)vv[u];
      const _Float16 l = (_Float16)(vv[u] - (float)h);
      hb[u] = __builtin_bit_cast(unsigned short, h);
      lb[u] = __builtin_bit_cast(unsigned short, l);
    }
    *(uint4*)&xh[nl][kg] = *(uint4*)hb;
    *(uint4*)&xl[nl][kg] = *(uint4*)lb;
    __syncthreads();
    const half8 wh =
        *(const half8*)(whi + (size_t)ca * 320 + kbase + quad * 8);
    const half8 wl =
        *(const half8*)(wlo + (size_t)ca * 320 + kbase + quad * 8);
#pragma unroll
    for (int nj = 0; nj < 4; ++nj) {
      const half8 bh = *(const half8*)&xh[nj * 16 + l15][quad * 8];
      const half8 bl = *(const half8*)&xl[nj * 16 + l15][quad * 8];
      f32x4 a = acc[nj];
      a = __builtin_amdgcn_mfma_f32_16x16x32_f16(wl, bh, a, 0, 0, 0);
      a = __builtin_amdgcn_mfma_f32_16x16x32_f16(wh, bl, a, 0, 0, 0);
      a = __builtin_amdgcn_mfma_f32_16x16x32_f16(wh, bh, a, 0, 0, 0);
      acc[nj] = a;
    }
  }

  const float invs = 1.0f / sqrtf(1.0f + 1e-5f);
#pragma unroll
  for (int r = 0; r < 4; ++r) {
    const int c = c0 + wv * 16 + quad * 4 + r;
    const float s = g5[c] * invs;
    const float bb = b5[c];
    float mx = -3.0e38f, sm = 0.0f;
#pragma unroll
    for (int nj = 0; nj < 4; ++nj) {
      float v = fmaf(s, acc[nj][r], bb);
      v = v > 0.0f ? v : 0.2f * v;
      mx = fmaxf(mx, v);
      sm += v;
    }
#pragma unroll
    for (int d = 1; d < 16; d <<= 1) {
      mx = fmaxf(mx, __shfl_xor(mx, d, 64));
      sm += __shfl_xor(sm, d, 64);
    }
    if (l15 == 0) {
      pmax[((size_t)b * 1024 + c) * 64 + nt] = mx;
      psum[((size_t)b * 1024 + c) * 64 + nt] = sm;
    }
  }
}

// ---- reduce partials -> gfeat [B][2048] = [gmax | gavg] ----
__global__ __launch_bounds__(256) void reduce5(const float* __restrict__ pmax,
                                               const float* __restrict__ psum,
                                               float* __restrict__ gfeat) {
  const int t = blockIdx.x * 256 + threadIdx.x;  // < 8192 = B*1024
  const int b = t >> 10, c = t & 1023;
  const float* pm = pmax + (size_t)t * 64;
  const float* ps = psum + (size_t)t * 64;
  float mx = -3.0e38f, sm = 0.0f;
  for (int i = 0; i < 64; i += 4) {
    const float4 v = *(const float4*)(pm + i);
    mx = fmaxf(mx, fmaxf(fmaxf(v.x, v.y), fmaxf(v.z, v.w)));
    const float4 u = *(const float4*)(ps + i);
    sm += (u.x + u.y) + (u.z + u.w);
  }
  gfeat[b * 2048 + c] = mx;
  gfeat[b * 2048 + 1024 + c] = sm * (1.0f / 4096.0f);
}

// ---- head: y1 = lrelu(bn(gfeat @ Wl1^T)) ----
__global__ __launch_bounds__(256) void head1(const float* __restrict__ gfeat,
                                             const float* __restrict__ Wl1,
                                             const float* __restrict__ g6,
                                             const float* __restrict__ b6,
                                             float* __restrict__ y1g) {
  __shared__ float gf[2048];
  __shared__ float red[256];
  const int tid = threadIdx.x;
  const int cb = blockIdx.x, b = blockIdx.y;
  const float4* gsrc = (const float4*)(gfeat + b * 2048);
  for (int p = tid; p < 512; p += 256) ((float4*)gf)[p] = gsrc[p];
  __syncthreads();
  const int cl = cb * 64 + (tid >> 2);
  const int q = tid & 3;
  const float* wr = Wl1 + (size_t)cl * 2048 + q * 512;
  const float* gq = gf + q * 512;
  float acc = 0.0f;
  for (int k0 = 0; k0 < 512; k0 += 8) {
    const float4 w0 = *(const float4*)(wr + k0);
    const float4 w1 = *(const float4*)(wr + k0 + 4);
    acc = fmaf(w0.x, gq[k0 + 0], acc); acc = fmaf(w0.y, gq[k0 + 1], acc);
    acc = fmaf(w0.z, gq[k0 + 2], acc); acc = fmaf(w0.w, gq[k0 + 3], acc);
    acc = fmaf(w1.x, gq[k0 + 4], acc); acc = fmaf(w1.y, gq[k0 + 5], acc);
    acc = fmaf(w1.z, gq[k0 + 6], acc); acc = fmaf(w1.w, gq[k0 + 7], acc);
  }
  red[tid] = acc;
  __syncthreads();
  if (q == 0) {
    float v = red[tid] + red[tid + 1] + red[tid + 2] + red[tid + 3];
    const float invs = 1.0f / sqrtf(1.0f + 1e-5f);
    v = fmaf(g6[cl] * invs, v, b6[cl]);
    v = v > 0.0f ? v : 0.2f * v;
    y1g[b * 512 + cl] = v;
  }
}

// ---- head: y2, y3, broadcast to [B][N][5] fp32 ----
__global__ __launch_bounds__(256) void head2(
    const float* __restrict__ y1g, const float* __restrict__ Wl2,
    const float* __restrict__ bl2, const float* __restrict__ g7,
    const float* __restrict__ b7, const float* __restrict__ Wl3,
    const float* __restrict__ bl3, float* __restrict__ out) {
  __shared__ float y1s[512];
  __shared__ float y2s[256];
  __shared__ float y3s[5];
  const int b = blockIdx.x;
  const int t = threadIdx.x;
  y1s[t] = y1g[b * 512 + t];
  y1s[t + 256] = y1g[b * 512 + t + 256];
  __syncthreads();
  {
    const float* wr = Wl2 + (size_t)t * 512;
    float acc = 0.0f;
    for (int k0 = 0; k0 < 512; k0 += 8) {
      const float4 w0 = *(const float4*)(wr + k0);
      const float4 w1 = *(const float4*)(wr + k0 + 4);
      acc = fmaf(w0.x, y1s[k0 + 0], acc); acc = fmaf(w0.y, y1s[k0 + 1], acc);
      acc = fmaf(w0.z, y1s[k0 + 2], acc); acc = fmaf(w0.w, y1s[k0 + 3], acc);
      acc = fmaf(w1.x, y1s[k0 + 4], acc); acc = fmaf(w1.y, y1s[k0 + 5], acc);
      acc = fmaf(w1.z, y1s[k0 + 6], acc); acc = fmaf(w1.w, y1s[k0 + 7], acc);
    }
    const float invs = 1.0f / sqrtf(1.0f + 1e-5f);
    float v = acc + bl2[t];
    v = fmaf(g7[t] * invs, v, b7[t]);
    v = v > 0.0f ? v : 0.2f * v;
    y2s[t] = v;
  }
  __syncthreads();
  if (t < 5) {
    const float* wr = Wl3 + (size_t)t * 256;
    float acc = 0.0f;
    for (int k = 0; k < 256; ++k) acc += wr[k] * y2s[k];
    y3s[t] = acc + bl3[t];
  }
  __syncthreads();
  for (int e = t; e < NPT * 5; e += 256)
    out[(size_t)b * (NPT * 5) + e] = y3s[e % 5];
}

extern "C" void kernel_launch(void* const* d_in, const int* in_sizes, int n_in,
                              void* d_out, int out_size, void* d_ws, size_t ws_size,
                              hipStream_t stream) {
  (void)in_sizes; (void)n_in; (void)out_size;
  const float* xyz = (const float*)d_in[0];
  const float* W1  = (const float*)d_in[1];
  const float* g1  = (const float*)d_in[2];
  const float* b1  = (const float*)d_in[3];
  const float* W2  = (const float*)d_in[4];
  const float* g2  = (const float*)d_in[5];
  const float* b2  = (const float*)d_in[6];
  const float* W3  = (const float*)d_in[7];
  const float* g3  = (const float*)d_in[8];
  const float* b3  = (const float*)d_in[9];
  const float* W4  = (const float*)d_in[10];
  const float* g4  = (const float*)d_in[11];
  const float* b4  = (const float*)d_in[12];
  const float* W5  = (const float*)d_in[13];
  const float* g5  = (const float*)d_in[14];
  const float* b5  = (const float*)d_in[15];
  const float* Wl1 = (const float*)d_in[16];
  const float* g6  = (const float*)d_in[17];
  const float* b6  = (const float*)d_in[18];
  const float* Wl2 = (const float*)d_in[19];
  const float* bl2 = (const float*)d_in[20];
  const float* g7  = (const float*)d_in[21];
  const float* b7  = (const float*)d_in[22];
  const float* Wl3 = (const float*)d_in[23];
  const float* bl3 = (const float*)d_in[24];

  char* ws = (char*)d_ws;
  float* x0    = (float*)(ws + 0);         //  524288 B
  float* x1    = (float*)(ws + 524288);    // 8388608 B
  float* x2    = (float*)(ws + 8912896);   // 8388608 B
  float* x3    = (float*)(ws + 17301504);  // 8388608 B
  float* x4    = (float*)(ws + 25690112);  // 16777216 B
  float* sqb   = (float*)(ws + 42467328);  //  131072 B
  int*   idxb  = (int*)  (ws + 42598400);  // 2621440 B
  float* pmx   = (float*)(ws + 45219840);  // 4194304 B (arena)
  float* psm   = (float*)(ws + 49414144);  // 4194304 B (arena)
  float* gfeat = (float*)(ws + 53608448);  //   65536 B
  float* y1g   = (float*)(ws + 53673984);  //   16384 B
  if (ws_size < 53690368) return;          // need ~51.2 MB scratch

  // arena (pmx..psm, 8 MB) time-shared: xhi/xlo during knn, Y during
  // featg/gather, pmax/psum partials during conv5/reduce5. idxb region
  // time-shared: neighbor indices during knn/gather, W5 hi/lo during conv5.
  unsigned short* xhi = (unsigned short*)pmx;
  unsigned short* xlo = (unsigned short*)psm;
  float* Yb = pmx;  // 8 MB: [32768][64] fp32
  unsigned short* whi = (unsigned short*)idxb;            // 655360 B
  unsigned short* wlo = (unsigned short*)idxb + 327680;   // 655360 B

  cvt_xyz<<<128, 256, 0, stream>>>(xyz, x0);

  knn3<<<512, 256, 65536, stream>>>(x0, idxb);
  featg3<<<2048, 256, 0, stream>>>(x0, W1, Yb);
  gather_edge<3, 4, 64><<<8192, 256, 0, stream>>>(x0, Yb, idxb, W1, g1, b1, x1, 0);

  sqsplit<<<512, 256, 0, stream>>>(x1, sqb, xhi, xlo);
  knn_mfma<<<512, 256, 65536, stream>>>(xhi, xlo, sqb, idxb);
  featg64<<<512, 256, 0, stream>>>(x1, W2, 0, Yb);
  gather_edge<64, 64, 64><<<8192, 256, 0, stream>>>(x1, Yb, idxb, W2, g2, b2, x2, 0);

  sqsplit<<<512, 256, 0, stream>>>(x2, sqb, xhi, xlo);
  knn_mfma<<<512, 256, 65536, stream>>>(xhi, xlo, sqb, idxb);
  featg64<<<512, 256, 0, stream>>>(x2, W3, 0, Yb);
  gather_edge<64, 64, 64><<<8192, 256, 0, stream>>>(x2, Yb, idxb, W3, g3, b3, x3, 0);

  sqsplit<<<512, 256, 0, stream>>>(x3, sqb, xhi, xlo);
  knn_mfma<<<512, 256, 65536, stream>>>(xhi, xlo, sqb, idxb);
  featg64<<<512, 256, 0, stream>>>(x3, W4, 0, Yb);
  gather_edge<64, 64, 128><<<8192, 256, 0, stream>>>(x3, Yb, idxb, W4, g4, b4, x4, 0);
  featg64<<<512, 256, 0, stream>>>(x3, W4, 64, Yb);
  gather_edge<64, 64, 128><<<8192, 256, 0, stream>>>(x3, Yb, idxb, W4, g4, b4, x4, 64);

  splitW5<<<320, 256, 0, stream>>>(W5, whi, wlo);
  conv5_mfma<<<dim3(64, 16, 8), 256, 0, stream>>>(x1, x2, x3, x4, whi, wlo,
                                                  g5, b5, pmx, psm);
  reduce5<<<32, 256, 0, stream>>>(pmx, psm, gfeat);
  head1<<<dim3(8, 8), 256, 0, stream>>>(gfeat, Wl1, g6, b6, y1g);
  head2<<<8, 256, 0, stream>>>(y1g, Wl2, bl2, g7, b7, Wl3, bl3, (float*)d_out);
}

// Round 14
// 2006.525 us; speedup vs baseline: 1.3484x; 1.0131x over previous
//
#include <hip/hip_runtime.h>

// DGCNN inference, MI355X gfx950. B=8, N=4096, K=20. fp32 in/out.
// r13 consolidation build (2033 us, reproduced) + sqsplit fused into
// gather_edge epilogue (lane = channel: hi/lo fp16 split of the output
// value + 64-lane shfl norm reduce). xhi/xlo relocated to the x4 region
// (dead during layers 1-3) to avoid aliasing Y. 3 launches + 72 MB of
// redundant traffic removed. knn/conv5 byte-identical to r13.

constexpr int NB  = 8;
constexpr int NPT = 4096;
constexpr int KNB = 20;
constexpr int CAP = 128;  // candidate buffer entries per row

typedef _Float16 half8 __attribute__((ext_vector_type(8)));
typedef float f32x4 __attribute__((ext_vector_type(4)));

// monotone float->uint map (order-preserving, handles negatives)
__device__ __forceinline__ unsigned int fmono(float f) {
  unsigned int u = __float_as_uint(f);
  return u ^ ((unsigned int)(((int)u) >> 31) | 0x80000000u);
}

// ---- full-wave bitonic: 64 smallest of buf[row][0..n), n <= 128, asc ----
// Lanes 0..63 end ascending; top-20 in lanes 0..19. u64 [64 rows][CAP].
__device__ __attribute__((noinline)) unsigned long long compact_row(
    int row, int n, int lane) {
  extern __shared__ char smem[];
  unsigned long long* buf = (unsigned long long*)smem + (size_t)row * CAP;
  const unsigned long long INFK = ~0ull;
  unsigned long long a = (lane < n) ? buf[lane] : INFK;
  unsigned long long c = (lane + 64 < n) ? buf[lane + 64] : INFK;
#pragma unroll
  for (int k = 2; k <= 64; k <<= 1) {
#pragma unroll
    for (int j = k >> 1; j > 0; j >>= 1) {
      const bool tm = (((lane & k) == 0) == ((lane & j) == 0));
      const unsigned long long oa = __shfl_xor(a, j, 64);
      a = ((a < oa) == tm) ? a : oa;  // ascending network
      const unsigned long long oc = __shfl_xor(c, j, 64);
      c = ((c < oc) == tm) ? oc : c;  // inverted -> descending
    }
  }
  unsigned long long m = a < c ? a : c;  // 64 smallest (bitonic)
#pragma unroll
  for (int j = 32; j > 0; j >>= 1) {  // merge to ascending
    const unsigned long long o = __shfl_xor(m, j, 64);
    const bool low = (lane & j) == 0;
    m = ((m < o) == low) ? m : o;
  }
  return m;
}

// ---- branch-free filter+append for 4 keys x 4 rows (one row per quad) ----
// base_r = w*16 + r; my quad's row = base_r + quad*4. tau/cnt in registers,
// quad-uniform. One uniform skip branch; compaction path is rare (exact).
__device__ __forceinline__ void sel4(unsigned long long k0,
                                     unsigned long long k1,
                                     unsigned long long k2,
                                     unsigned long long k3, int base_r,
                                     int quad, int lane, unsigned int below,
                                     unsigned long long& tau, int& cnt) {
  extern __shared__ char smem[];
  unsigned long long* bufB = (unsigned long long*)smem;
#pragma unroll 1
  for (int attempt = 0; attempt < 2; ++attempt) {
    const unsigned long long m0 = __ballot(k0 < tau);
    const unsigned long long m1 = __ballot(k1 < tau);
    const unsigned long long m2 = __ballot(k2 < tau);
    const unsigned long long m3 = __ballot(k3 < tau);
    if ((m0 | m1 | m2 | m3) == 0ull) return;  // uniform: nothing anywhere
    const int sh = quad * 16;
    const unsigned int s0 = (unsigned int)(m0 >> sh) & 0xFFFFu;
    const unsigned int s1 = (unsigned int)(m1 >> sh) & 0xFFFFu;
    const unsigned int s2 = (unsigned int)(m2 >> sh) & 0xFFFFu;
    const unsigned int s3 = (unsigned int)(m3 >> sh) & 0xFFFFu;
    const int tot = __popc(s0) + __popc(s1) + __popc(s2) + __popc(s3);
    const unsigned long long needm = __ballot(cnt + tot > CAP);
    if (needm != 0ull && attempt == 0) {  // rare: compact overflowing rows
#pragma unroll 1
      for (int q = 0; q < 4; ++q) {
        if ((needm >> (q * 16)) & 1ull) {
          const int nq = __shfl(cnt, q * 16, 64);
          const unsigned long long sv = compact_row(base_r + q * 4, nq, lane);
          const unsigned long long t19 = __shfl(sv, 19, 64);
          if (lane < 20) bufB[(size_t)(base_r + q * 4) * CAP + lane] = sv;
          if (quad == q) { tau = t19; cnt = 20; }
        }
      }
      continue;  // retry with tightened tau (guaranteed fit)
    }
    int pos = cnt + __popc(s0 & below) + __popc(s1 & below) +
              __popc(s2 & below) + __popc(s3 & below);
    unsigned long long* bp = bufB + (size_t)(base_r + quad * 4) * CAP;
    if (k0 < tau) { bp[pos] = k0; ++pos; }
    if (k1 < tau) { bp[pos] = k1; ++pos; }
    if (k2 < tau) { bp[pos] = k2; ++pos; }
    if (k3 < tau) { bp[pos] = k3; }
    cnt += tot;
    return;
  }
}

// ---- convert xyz fp32 [B][N][3] -> fp32 [B][N][4] (pad 0) ----
__global__ __launch_bounds__(256) void cvt_xyz(const float* __restrict__ xyz,
                                               float* __restrict__ x0) {
  const int t = blockIdx.x * 256 + threadIdx.x;  // < B*N
  float4 v;
  v.x = xyz[t * 3 + 0];
  v.y = xyz[t * 3 + 1];
  v.z = xyz[t * 3 + 2];
  v.w = 0.0f;
  *(float4*)(x0 + (size_t)t * 4) = v;
}

// ---- knn layer 1 (D=3): direct distances, xj register double-buffer ----
// Grid 512: b = bid&7 (XCD pin), i0 = (bid>>3)*64. dyn LDS 65536 B.
__global__ __launch_bounds__(256, 2) void knn3(const float* __restrict__ x0,
                                               int* __restrict__ idxout) {
  const int bid = blockIdx.x;
  const int b = bid & 7;
  const int i0 = (bid >> 3) * 64;
  const int tid = threadIdx.x, w = tid >> 6, lane = tid & 63;
  const int l15 = lane & 15, quad = lane >> 4;
  const unsigned int below = (1u << l15) - 1u;
  const float* xb = x0 + (size_t)b * (NPT * 4);

  float xix[4], xiy[4], xiz[4];
#pragma unroll
  for (int r = 0; r < 4; ++r) {
    const float4 v =
        *(const float4*)(xb + (size_t)(i0 + w * 16 + quad * 4 + r) * 4);
    xix[r] = v.x;
    xiy[r] = v.y;
    xiz[r] = v.z;
  }

  unsigned long long tau[4] = {~0ull, ~0ull, ~0ull, ~0ull};
  int cnt[4] = {0, 0, 0, 0};

  float4 cj[4];
#pragma unroll
  for (int nj = 0; nj < 4; ++nj)
    cj[nj] = *(const float4*)(xb + (size_t)(nj * 16 + l15) * 4);

  for (int jt = 0; jt < NPT / 64; ++jt) {
    const int j0 = jt * 64;
    // prefetch next tile (overlaps with the sel phase below)
    float4 nj4[4];
    {
      const int jn0 = (jt + 1 < NPT / 64 ? jt + 1 : jt) * 64;
#pragma unroll
      for (int nj = 0; nj < 4; ++nj)
        nj4[nj] = *(const float4*)(xb + (size_t)(jn0 + nj * 16 + l15) * 4);
    }
#pragma unroll
    for (int r = 0; r < 4; ++r) {
      unsigned long long k[4];
#pragma unroll
      for (int nj = 0; nj < 4; ++nj) {
        const float dx = cj[nj].x - xix[r];
        const float dy = cj[nj].y - xiy[r];
        const float dz = cj[nj].z - xiz[r];
        const float dd = fmaf(dx, dx, fmaf(dy, dy, dz * dz));
        k[nj] = ((unsigned long long)fmono(dd) << 32) |
                (unsigned int)(j0 + nj * 16 + l15);
      }
      sel4(k[0], k[1], k[2], k[3], w * 16 + r, quad, lane, below, tau[r],
           cnt[r]);
    }
#pragma unroll
    for (int nj = 0; nj < 4; ++nj) cj[nj] = nj4[nj];
  }
#pragma unroll 1
  for (int rw = 0; rw < 16; ++rw) {
    const int q = rw >> 2, r = rw & 3;
    const int nq = __shfl(cnt[r], q * 16, 64);
    const unsigned long long sv = compact_row(w * 16 + rw, nq, lane);
    const int i = i0 + w * 16 + rw;
    if (lane < 20)
      idxout[((size_t)(b * NPT + i)) * KNB + lane] = (int)(unsigned int)sv;
  }
}

// ---- knn layers 2-4 (D=64): fp16x2-split MFMA, B-frag double-buffer ----
// Grid 512: b = bid&7 (XCD pin -> 2MB/batch L2-resident). dyn LDS 65536 B.
__global__ __launch_bounds__(256, 2) void knn_mfma(
    const unsigned short* __restrict__ xhi16,
    const unsigned short* __restrict__ xlo16,
    const float* __restrict__ sqn, int* __restrict__ idxout) {
  const int bid = blockIdx.x;
  const int b = bid & 7;
  const int i0 = (bid >> 3) * 64;
  const int tid = threadIdx.x, w = tid >> 6, lane = tid & 63;
  const int l15 = lane & 15, quad = lane >> 4;
  const unsigned int below = (1u << l15) - 1u;

  const half8* Hb = (const half8*)(xhi16 + (size_t)b * NPT * 64);
  const half8* Lb = (const half8*)(xlo16 + (size_t)b * NPT * 64);
  const float* sqb = sqn + b * NPT;

  const int ia = i0 + w * 16 + l15;
  const half8 ah0 = Hb[(size_t)ia * 8 + quad];
  const half8 ah1 = Hb[(size_t)ia * 8 + 4 + quad];
  const half8 al0 = Lb[(size_t)ia * 8 + quad];
  const half8 al1 = Lb[(size_t)ia * 8 + 4 + quad];

  unsigned long long tau[4] = {~0ull, ~0ull, ~0ull, ~0ull};
  int cnt[4] = {0, 0, 0, 0};

  // B-fragment double buffer: cb = current tile, loaded for jt=0 here
  half8 cb[16];
  float sqc[4];
#pragma unroll
  for (int nj = 0; nj < 4; ++nj) {
    const int jb = nj * 16 + l15;
    cb[nj * 4 + 0] = Hb[(size_t)jb * 8 + quad];
    cb[nj * 4 + 1] = Hb[(size_t)jb * 8 + 4 + quad];
    cb[nj * 4 + 2] = Lb[(size_t)jb * 8 + quad];
    cb[nj * 4 + 3] = Lb[(size_t)jb * 8 + 4 + quad];
    sqc[nj] = sqb[nj * 16 + l15];
  }

  for (int jt = 0; jt < NPT / 64; ++jt) {
    const int j0 = jt * 64;
    // issue next-tile loads first: latency hides under MFMA + sel below
    half8 nb[16];
    float sqn4[4];
    {
      const int jn0 = (jt + 1 < NPT / 64 ? jt + 1 : jt) * 64;
#pragma unroll
      for (int nj = 0; nj < 4; ++nj) {
        const int jb = jn0 + nj * 16 + l15;
        nb[nj * 4 + 0] = Hb[(size_t)jb * 8 + quad];
        nb[nj * 4 + 1] = Hb[(size_t)jb * 8 + 4 + quad];
        nb[nj * 4 + 2] = Lb[(size_t)jb * 8 + quad];
        nb[nj * 4 + 3] = Lb[(size_t)jb * 8 + 4 + quad];
        sqn4[nj] = sqb[jn0 + nj * 16 + l15];
      }
    }
    f32x4 acc[4];
#pragma unroll
    for (int nj = 0; nj < 4; ++nj) {
      f32x4 a = {0.0f, 0.0f, 0.0f, 0.0f};
      a = __builtin_amdgcn_mfma_f32_16x16x32_f16(al0, cb[nj * 4 + 0], a, 0, 0, 0);
      a = __builtin_amdgcn_mfma_f32_16x16x32_f16(al1, cb[nj * 4 + 1], a, 0, 0, 0);
      a = __builtin_amdgcn_mfma_f32_16x16x32_f16(ah0, cb[nj * 4 + 2], a, 0, 0, 0);
      a = __builtin_amdgcn_mfma_f32_16x16x32_f16(ah1, cb[nj * 4 + 3], a, 0, 0, 0);
      a = __builtin_amdgcn_mfma_f32_16x16x32_f16(ah0, cb[nj * 4 + 0], a, 0, 0, 0);
      a = __builtin_amdgcn_mfma_f32_16x16x32_f16(ah1, cb[nj * 4 + 1], a, 0, 0, 0);
      acc[nj] = a;
    }
    // C layout: row = quad*4+r, col = nj*16+l15
#pragma unroll
    for (int r = 0; r < 4; ++r) {
      unsigned long long k[4];
#pragma unroll
      for (int nj = 0; nj < 4; ++nj) {
        const float dd = fmaf(-2.0f, acc[nj][r], sqc[nj]);
        k[nj] = ((unsigned long long)fmono(dd) << 32) |
                (unsigned int)(j0 + nj * 16 + l15);
      }
      sel4(k[0], k[1], k[2], k[3], w * 16 + r, quad, lane, below, tau[r],
           cnt[r]);
    }
#pragma unroll
    for (int e = 0; e < 16; ++e) cb[e] = nb[e];
#pragma unroll
    for (int nj = 0; nj < 4; ++nj) sqc[nj] = sqn4[nj];
  }
#pragma unroll 1
  for (int rw = 0; rw < 16; ++rw) {
    const int q = rw >> 2, r = rw & 3;
    const int nq = __shfl(cnt[r], q * 16, 64);
    const unsigned long long sv = compact_row(w * 16 + rw, nq, lane);
    const int i = i0 + w * 16 + rw;
    if (lane < 20)
      idxout[((size_t)(b * NPT + i)) * KNB + lane] = (int)(unsigned int)sv;
  }
}

// ---- featg3: Y[p, c] = wa_c . x0[p]  (DIN=3), XCD-pinned ----
__global__ __launch_bounds__(256) void featg3(const float* __restrict__ x0,
                                              const float* __restrict__ W,
                                              float* __restrict__ Y) {
  const int lane = threadIdx.x & 63;
  const int bid = blockIdx.x;  // 2048 = 8 x 256
  const int p0 =
      ((bid & 7) << 12) + ((bid >> 3) * 4 + (threadIdx.x >> 6)) * 4;
  const float* wr = W + lane * 6;
  const float w0 = wr[0], w1 = wr[1], w2 = wr[2];
#pragma unroll
  for (int r = 0; r < 4; ++r) {
    const float4 v = *(const float4*)(x0 + (size_t)(p0 + r) * 4);
    Y[(size_t)(p0 + r) * 64 + lane] = w0 * v.x + w1 * v.y + w2 * v.z;
  }
}

// ---- featg64: Y[p, c'] = sum_d X[p][d] * W[(co+c')][d], XCD-pinned ----
__global__ __launch_bounds__(256) void featg64(const float* __restrict__ X,
                                               const float* __restrict__ W,
                                               int co, float* __restrict__ Y) {
  __shared__ float Xt[64][68];  // [d][p]
  __shared__ float Wt[64][68];  // [d][c]
  const int tid = threadIdx.x;
  const int bid = blockIdx.x;  // 512 = 8 x 64
  const int n0 = ((bid & 7) << 12) + (bid >> 3) * 64;
  const int pc = tid & 63, dg = tid >> 6;  // dg 0..3
#pragma unroll
  for (int rep = 0; rep < 4; ++rep) {
    const int d0 = dg * 16 + rep * 4;
    const float4 xv = *(const float4*)(X + (size_t)(n0 + pc) * 64 + d0);
    Xt[d0 + 0][pc] = xv.x; Xt[d0 + 1][pc] = xv.y;
    Xt[d0 + 2][pc] = xv.z; Xt[d0 + 3][pc] = xv.w;
    const float4 wv = *(const float4*)(W + (size_t)(co + pc) * 128 + d0);
    Wt[d0 + 0][pc] = wv.x; Wt[d0 + 1][pc] = wv.y;
    Wt[d0 + 2][pc] = wv.z; Wt[d0 + 3][pc] = wv.w;
  }
  __syncthreads();
  const int c0 = (tid & 15) * 4, p0 = (tid >> 4) * 4;
  float acc[4][4];
#pragma unroll
  for (int i = 0; i < 4; ++i)
#pragma unroll
    for (int j = 0; j < 4; ++j) acc[i][j] = 0.0f;
#pragma unroll 4
  for (int d = 0; d < 64; ++d) {
    const float4 xa = *(const float4*)&Xt[d][p0];
    const float4 wc = *(const float4*)&Wt[d][c0];
    const float xr[4] = {xa.x, xa.y, xa.z, xa.w};
    const float wr[4] = {wc.x, wc.y, wc.z, wc.w};
#pragma unroll
    for (int i = 0; i < 4; ++i)
#pragma unroll
      for (int j = 0; j < 4; ++j) acc[i][j] = fmaf(xr[i], wr[j], acc[i][j]);
  }
#pragma unroll
  for (int i = 0; i < 4; ++i) {
    float4 o;
    o.x = acc[i][0]; o.y = acc[i][1]; o.z = acc[i][2]; o.w = acc[i][3];
    *(float4*)(Y + (size_t)(n0 + p0 + i) * 64 + c0) = o;
  }
}

// ---- gather_edge: out[n, co+c] = max_k lrelu(s*(Y[j,c] + D[n,c]) + bias) --
// SPLIT=1 (COUT=64 only): fused sqsplit epilogue - hi/lo fp16 split of the
// output value + 64-lane shfl norm reduce (identical arithmetic to the old
// sqsplit kernel; lane = channel).
template <int DIN, int DS, int COUT, int SPLIT>
__global__ __launch_bounds__(256) void gather_edge(
    const float* __restrict__ x, const float* __restrict__ Y,
    const int* __restrict__ idx, const float* __restrict__ W,
    const float* __restrict__ g, const float* __restrict__ bia,
    float* __restrict__ out, int co, float* __restrict__ sqo,
    unsigned short* __restrict__ xhi, unsigned short* __restrict__ xlo) {
  const int lane = threadIdx.x & 63;
  const int bid = blockIdx.x;  // 8192 = 8 x 1024
  const int wglob = ((bid & 7) << 12) + (bid >> 3) * 4 + (threadIdx.x >> 6);
  const int b = wglob >> 12;
  const int c = co + lane;

  const float* wrow = W + (size_t)c * (2 * DIN);
  const float* xi = x + (size_t)wglob * DS;
  float Dv = 0.0f;
  if constexpr (DIN == 3) {
    const float4 v = *(const float4*)xi;
    Dv = (wrow[3] - wrow[0]) * v.x + (wrow[4] - wrow[1]) * v.y +
         (wrow[5] - wrow[2]) * v.z;
  } else {
#pragma unroll
    for (int d0 = 0; d0 < DIN; d0 += 4) {
      const float4 wa4 = *(const float4*)(wrow + d0);
      const float4 wb4 = *(const float4*)(wrow + DIN + d0);
      const float4 v = *(const float4*)(xi + d0);
      Dv += (wb4.x - wa4.x) * v.x + (wb4.y - wa4.y) * v.y +
            (wb4.z - wa4.z) * v.z + (wb4.w - wa4.w) * v.w;
    }
  }
  const float invs = 1.0f / sqrtf(1.0f + 1e-5f);
  const float s = g[c] * invs;
  const float base = fmaf(s, Dv, bia[c]);

  const int* ip = idx + (size_t)wglob * KNB;
  const int jv = ip[lane < KNB ? lane : 0];
  const float* Yb = Y + (((size_t)b) << 12) * 64;
  float m = -3.0e38f;
#pragma unroll
  for (int k = 0; k < KNB; ++k) {
    const int j = __shfl(jv, k, 64);
    const float yv = Yb[(size_t)j * 64 + lane];
    float v = fmaf(s, yv, base);
    v = v > 0.0f ? v : 0.2f * v;
    m = fmaxf(m, v);
  }
  out[(size_t)wglob * COUT + c] = m;
  if constexpr (SPLIT) {
    float ssq = m * m;
#pragma unroll
    for (int d = 1; d < 64; d <<= 1) ssq += __shfl_xor(ssq, d, 64);
    const _Float16 h = (_Float16)m;
    const _Float16 l = (_Float16)(m - (float)h);
    xhi[(size_t)wglob * 64 + lane] = __builtin_bit_cast(unsigned short, h);
    xlo[(size_t)wglob * 64 + lane] = __builtin_bit_cast(unsigned short, l);
    if (lane == 0) sqo[wglob] = ssq;
  }
}

// ---- split W5 [1024][320] fp32 -> hi/lo fp16 ----
__global__ __launch_bounds__(256) void splitW5(
    const float* __restrict__ W5, unsigned short* __restrict__ whi,
    unsigned short* __restrict__ wlo) {
  const int t = blockIdx.x * 256 + threadIdx.x;  // < 81920 = 1024*320/4
  const float4 v = *(const float4*)(W5 + (size_t)t * 4);
  const float vv[4] = {v.x, v.y, v.z, v.w};
  unsigned short hb[4], lb[4];
#pragma unroll
  for (int u = 0; u < 4; ++u) {
    const _Float16 h = (_Float16)vv[u];
    const _Float16 l = (_Float16)(vv[u] - (float)h);
    hb[u] = __builtin_bit_cast(unsigned short, h);
    lb[u] = __builtin_bit_cast(unsigned short, l);
  }
  *(uint2*)(whi + (size_t)t * 4) = *(uint2*)hb;
  *(uint2*)(wlo + (size_t)t * 4) = *(uint2*)lb;
}

// ---- conv5 via fp16-split MFMA: H = Xc(32768x320) @ W5^T, fused pooling --
__global__ __launch_bounds__(256) void conv5_mfma(
    const float* __restrict__ x1, const float* __restrict__ x2,
    const float* __restrict__ x3, const float* __restrict__ x4,
    const unsigned short* __restrict__ whi,
    const unsigned short* __restrict__ wlo, const float* __restrict__ g5,
    const float* __restrict__ b5, float* __restrict__ pmax,
    float* __restrict__ psum) {
  __shared__ __align__(16) unsigned short xh[64][40];
  __shared__ __align__(16) unsigned short xl[64][40];
  const int nt = blockIdx.x, ct = blockIdx.y, b = blockIdx.z;
  const int tid = threadIdx.x, wv = tid >> 6, lane = tid & 63;
  const int l15 = lane & 15, quad = lane >> 4;
  const int n0 = nt * 64, c0 = ct * 64;

  const int nl = tid >> 2;         // loader: n row 0..63
  const int kg = (tid & 3) * 8;    // loader: k group {0,8,16,24}

  f32x4 acc[4];
#pragma unroll
  for (int nj = 0; nj < 4; ++nj) acc[nj] = {0.0f, 0.0f, 0.0f, 0.0f};

  const int ca = c0 + wv * 16 + l15;  // A-frag row (c)

  for (int kt = 0; kt < 10; ++kt) {
    __syncthreads();  // prev MFMA reads done before overwrite
    const int kbase = kt * 32;
    const float* src;
    int koff;
    if (kbase < 64)       { src = x1 + ((size_t)(b * NPT + n0 + nl)) * 64;  koff = kbase; }
    else if (kbase < 128) { src = x2 + ((size_t)(b * NPT + n0 + nl)) * 64;  koff = kbase - 64; }
    else if (kbase < 192) { src = x3 + ((size_t)(b * NPT + n0 + nl)) * 64;  koff = kbase - 128; }
    else                  { src = x4 + ((size_t)(b * NPT + n0 + nl)) * 128; koff = kbase - 192; }
    const float4 v0 = *(const float4*)(src + koff + kg);
    const float4 v1 = *(const float4*)(src + koff + kg + 4);
    const float vv[8] = {v0.x, v0.y, v0.z, v0.w, v1.x, v1.y, v1.z, v1.w};
    unsigned short hb[8], lb[8];
#pragma unroll
    for (int u = 0; u < 8; ++u) {
      const _Float16 h = (_Float16)vv[u];
      const _Float16 l = (_Float16)(vv[u] - (float)h);
      hb[u] = __builtin_bit_cast(unsigned short, h);
      lb[u] = __builtin_bit_cast(unsigned short, l);
    }
    *(uint4*)&xh[nl][kg] = *(uint4*)hb;
    *(uint4*)&xl[nl][kg] = *(uint4*)lb;
    __syncthreads();
    const half8 wh =
        *(const half8*)(whi + (size_t)ca * 320 + kbase + quad * 8);
    const half8 wl =
        *(const half8*)(wlo + (size_t)ca * 320 + kbase + quad * 8);
#pragma unroll
    for (int nj = 0; nj < 4; ++nj) {
      const half8 bh = *(const half8*)&xh[nj * 16 + l15][quad * 8];
      const half8 bl = *(const half8*)&xl[nj * 16 + l15][quad * 8];
      f32x4 a = acc[nj];
      a = __builtin_amdgcn_mfma_f32_16x16x32_f16(wl, bh, a, 0, 0, 0);
      a = __builtin_amdgcn_mfma_f32_16x16x32_f16(wh, bl, a, 0, 0, 0);
      a = __builtin_amdgcn_mfma_f32_16x16x32_f16(wh, bh, a, 0, 0, 0);
      acc[nj] = a;
    }
  }

  const float invs = 1.0f / sqrtf(1.0f + 1e-5f);
#pragma unroll
  for (int r = 0; r < 4; ++r) {
    const int c = c0 + wv * 16 + quad * 4 + r;
    const float s = g5[c] * invs;
    const float bb = b5[c];
    float mx = -3.0e38f, sm = 0.0f;
#pragma unroll
    for (int nj = 0; nj < 4; ++nj) {
      float v = fmaf(s, acc[nj][r], bb);
      v = v > 0.0f ? v : 0.2f * v;
      mx = fmaxf(mx, v);
      sm += v;
    }
#pragma unroll
    for (int d = 1; d < 16; d <<= 1) {
      mx = fmaxf(mx, __shfl_xor(mx, d, 64));
      sm += __shfl_xor(sm, d, 64);
    }
    if (l15 == 0) {
      pmax[((size_t)b * 1024 + c) * 64 + nt] = mx;
      psum[((size_t)b * 1024 + c) * 64 + nt] = sm;
    }
  }
}

// ---- reduce partials -> gfeat [B][2048] = [gmax | gavg] ----
__global__ __launch_bounds__(256) void reduce5(const float* __restrict__ pmax,
                                               const float* __restrict__ psum,
                                               float* __restrict__ gfeat) {
  const int t = blockIdx.x * 256 + threadIdx.x;  // < 8192 = B*1024
  const int b = t >> 10, c = t & 1023;
  const float* pm = pmax + (size_t)t * 64;
  const float* ps = psum + (size_t)t * 64;
  float mx = -3.0e38f, sm = 0.0f;
  for (int i = 0; i < 64; i += 4) {
    const float4 v = *(const float4*)(pm + i);
    mx = fmaxf(mx, fmaxf(fmaxf(v.x, v.y), fmaxf(v.z, v.w)));
    const float4 u = *(const float4*)(ps + i);
    sm += (u.x + u.y) + (u.z + u.w);
  }
  gfeat[b * 2048 + c] = mx;
  gfeat[b * 2048 + 1024 + c] = sm * (1.0f / 4096.0f);
}

// ---- head: y1 = lrelu(bn(gfeat @ Wl1^T)) ----
__global__ __launch_bounds__(256) void head1(const float* __restrict__ gfeat,
                                             const float* __restrict__ Wl1,
                                             const float* __restrict__ g6,
                                             const float* __restrict__ b6,
                                             float* __restrict__ y1g) {
  __shared__ float gf[2048];
  __shared__ float red[256];
  const int tid = threadIdx.x;
  const int cb = blockIdx.x, b = blockIdx.y;
  const float4* gsrc = (const float4*)(gfeat + b * 2048);
  for (int p = tid; p < 512; p += 256) ((float4*)gf)[p] = gsrc[p];
  __syncthreads();
  const int cl = cb * 64 + (tid >> 2);
  const int q = tid & 3;
  const float* wr = Wl1 + (size_t)cl * 2048 + q * 512;
  const float* gq = gf + q * 512;
  float acc = 0.0f;
  for (int k0 = 0; k0 < 512; k0 += 8) {
    const float4 w0 = *(const float4*)(wr + k0);
    const float4 w1 = *(const float4*)(wr + k0 + 4);
    acc = fmaf(w0.x, gq[k0 + 0], acc); acc = fmaf(w0.y, gq[k0 + 1], acc);
    acc = fmaf(w0.z, gq[k0 + 2], acc); acc = fmaf(w0.w, gq[k0 + 3], acc);
    acc = fmaf(w1.x, gq[k0 + 4], acc); acc = fmaf(w1.y, gq[k0 + 5], acc);
    acc = fmaf(w1.z, gq[k0 + 6], acc); acc = fmaf(w1.w, gq[k0 + 7], acc);
  }
  red[tid] = acc;
  __syncthreads();
  if (q == 0) {
    float v = red[tid] + red[tid + 1] + red[tid + 2] + red[tid + 3];
    const float invs = 1.0f / sqrtf(1.0f + 1e-5f);
    v = fmaf(g6[cl] * invs, v, b6[cl]);
    v = v > 0.0f ? v : 0.2f * v;
    y1g[b * 512 + cl] = v;
  }
}

// ---- head: y2, y3, broadcast to [B][N][5] fp32 ----
__global__ __launch_bounds__(256) void head2(
    const float* __restrict__ y1g, const float* __restrict__ Wl2,
    const float* __restrict__ bl2, const float* __restrict__ g7,
    const float* __restrict__ b7, const float* __restrict__ Wl3,
    const float* __restrict__ bl3, float* __restrict__ out) {
  __shared__ float y1s[512];
  __shared__ float y2s[256];
  __shared__ float y3s[5];
  const int b = blockIdx.x;
  const int t = threadIdx.x;
  y1s[t] = y1g[b * 512 + t];
  y1s[t + 256] = y1g[b * 512 + t + 256];
  __syncthreads();
  {
    const float* wr = Wl2 + (size_t)t * 512;
    float acc = 0.0f;
    for (int k0 = 0; k0 < 512; k0 += 8) {
      const float4 w0 = *(const float4*)(wr + k0);
      const float4 w1 = *(const float4*)(wr + k0 + 4);
      acc = fmaf(w0.x, y1s[k0 + 0], acc); acc = fmaf(w0.y, y1s[k0 + 1], acc);
      acc = fmaf(w0.z, y1s[k0 + 2], acc); acc = fmaf(w0.w, y1s[k0 + 3], acc);
      acc = fmaf(w1.x, y1s[k0 + 4], acc); acc = fmaf(w1.y, y1s[k0 + 5], acc);
      acc = fmaf(w1.z, y1s[k0 + 6], acc); acc = fmaf(w1.w, y1s[k0 + 7], acc);
    }
    const float invs = 1.0f / sqrtf(1.0f + 1e-5f);
    float v = acc + bl2[t];
    v = fmaf(g7[t] * invs, v, b7[t]);
    v = v > 0.0f ? v : 0.2f * v;
    y2s[t] = v;
  }
  __syncthreads();
  if (t < 5) {
    const float* wr = Wl3 + (size_t)t * 256;
    float acc = 0.0f;
    for (int k = 0; k < 256; ++k) acc += wr[k] * y2s[k];
    y3s[t] = acc + bl3[t];
  }
  __syncthreads();
  for (int e = t; e < NPT * 5; e += 256)
    out[(size_t)b * (NPT * 5) + e] = y3s[e % 5];
}

extern "C" void kernel_launch(void* const* d_in, const int* in_sizes, int n_in,
                              void* d_out, int out_size, void* d_ws, size_t ws_size,
                              hipStream_t stream) {
  (void)in_sizes; (void)n_in; (void)out_size;
  const float* xyz = (const float*)d_in[0];
  const float* W1  = (const float*)d_in[1];
  const float* g1  = (const float*)d_in[2];
  const float* b1  = (const float*)d_in[3];
  const float* W2  = (const float*)d_in[4];
  const float* g2  = (const float*)d_in[5];
  const float* b2  = (const float*)d_in[6];
  const float* W3  = (const float*)d_in[7];
  const float* g3  = (const float*)d_in[8];
  const float* b3  = (const float*)d_in[9];
  const float* W4  = (const float*)d_in[10];
  const float* g4  = (const float*)d_in[11];
  const float* b4  = (const float*)d_in[12];
  const float* W5  = (const float*)d_in[13];
  const float* g5  = (const float*)d_in[14];
  const float* b5  = (const float*)d_in[15];
  const float* Wl1 = (const float*)d_in[16];
  const float* g6  = (const float*)d_in[17];
  const float* b6  = (const float*)d_in[18];
  const float* Wl2 = (const float*)d_in[19];
  const float* bl2 = (const float*)d_in[20];
  const float* g7  = (const float*)d_in[21];
  const float* b7  = (const float*)d_in[22];
  const float* Wl3 = (const float*)d_in[23];
  const float* bl3 = (const float*)d_in[24];

  char* ws = (char*)d_ws;
  float* x0    = (float*)(ws + 0);         //  524288 B
  float* x1    = (float*)(ws + 524288);    // 8388608 B
  float* x2    = (float*)(ws + 8912896);   // 8388608 B
  float* x3    = (float*)(ws + 17301504);  // 8388608 B
  float* x4    = (float*)(ws + 25690112);  // 16777216 B
  float* sqb   = (float*)(ws + 42467328);  //  131072 B
  int*   idxb  = (int*)  (ws + 42598400);  // 2621440 B
  float* pmx   = (float*)(ws + 45219840);  // 4194304 B (arena)
  float* psm   = (float*)(ws + 49414144);  // 4194304 B (arena)
  float* gfeat = (float*)(ws + 53608448);  //   65536 B
  float* y1g   = (float*)(ws + 53673984);  //   16384 B
  if (ws_size < 53690368) return;          // need ~51.2 MB scratch

  // Yb (8 MB) = pmx..psm, used by featg/gather; pmax/psum partials reuse
  // pmx/psm during conv5/reduce5. xhi/xlo (4 MB each) live in the x4
  // region, which is dead until layer-4's gather (stream-ordered after the
  // last knn consumes them). idxb region time-shared with W5 hi/lo.
  float* Yb = pmx;  // 8 MB: [32768][64] fp32
  unsigned short* xhi = (unsigned short*)x4;             // 4 MB
  unsigned short* xlo = (unsigned short*)x4 + 2097152;   // 4 MB
  unsigned short* whi = (unsigned short*)idxb;            // 655360 B
  unsigned short* wlo = (unsigned short*)idxb + 327680;   // 655360 B

  cvt_xyz<<<128, 256, 0, stream>>>(xyz, x0);

  knn3<<<512, 256, 65536, stream>>>(x0, idxb);
  featg3<<<2048, 256, 0, stream>>>(x0, W1, Yb);
  gather_edge<3, 4, 64, 1><<<8192, 256, 0, stream>>>(
      x0, Yb, idxb, W1, g1, b1, x1, 0, sqb, xhi, xlo);

  knn_mfma<<<512, 256, 65536, stream>>>(xhi, xlo, sqb, idxb);
  featg64<<<512, 256, 0, stream>>>(x1, W2, 0, Yb);
  gather_edge<64, 64, 64, 1><<<8192, 256, 0, stream>>>(
      x1, Yb, idxb, W2, g2, b2, x2, 0, sqb, xhi, xlo);

  knn_mfma<<<512, 256, 65536, stream>>>(xhi, xlo, sqb, idxb);
  featg64<<<512, 256, 0, stream>>>(x2, W3, 0, Yb);
  gather_edge<64, 64, 64, 1><<<8192, 256, 0, stream>>>(
      x2, Yb, idxb, W3, g3, b3, x3, 0, sqb, xhi, xlo);

  knn_mfma<<<512, 256, 65536, stream>>>(xhi, xlo, sqb, idxb);
  featg64<<<512, 256, 0, stream>>>(x3, W4, 0, Yb);
  gather_edge<64, 64, 128, 0><<<8192, 256, 0, stream>>>(
      x3, Yb, idxb, W4, g4, b4, x4, 0, nullptr, nullptr, nullptr);
  featg64<<<512, 256, 0, stream>>>(x3, W4, 64, Yb);
  gather_edge<64, 64, 128, 0><<<8192, 256, 0, stream>>>(
      x3, Yb, idxb, W4, g4, b4, x4, 64, nullptr, nullptr, nullptr);

  splitW5<<<320, 256, 0, stream>>>(W5, whi, wlo);
  conv5_mfma<<<dim3(64, 16, 8), 256, 0, stream>>>(x1, x2, x3, x4, whi, wlo,
                                                  g5, b5, pmx, psm);
  reduce5<<<32, 256, 0, stream>>>(pmx, psm, gfeat);
  head1<<<dim3(8, 8), 256, 0, stream>>>(gfeat, Wl1, g6, b6, y1g);
  head2<<<8, 256, 0, stream>>>(y1g, Wl2, bl2, g7, b7, Wl3, bl3, (float*)d_out);
}